// Round 6
// baseline (1334.115 us; speedup 1.0000x reference)
//
#include <hip/hip_runtime.h>
#include <math.h>

#define NB 32
#define NG 512
#define NC 384
#define NH 768

// ---------------- GEMM: C = op(A @ Bw + bias), A: MxK row-major, Bw: KxN row-major
// mode 0: relu      mode 1: divide by 0.1 (scores / TAU)
__global__ __launch_bounds__(256) void gemm_bias(
    const float* __restrict__ A, const float* __restrict__ Bw,
    const float* __restrict__ bias, float* __restrict__ Co,
    int M, int N, int K, int mode)
{
    __shared__ float sA[16][64];
    __shared__ float sB[16][64];
    int mtiles = M >> 6;
    int bm = (blockIdx.x % mtiles) << 6;
    int bn = (blockIdx.x / mtiles) << 6;
    int t = threadIdx.x;
    int tx = t & 15, ty = t >> 4;
    int la_m = t >> 2;          // 0..63
    int la_q = (t & 3) << 2;    // k offset 0,4,8,12
    int lb_k = t >> 4;          // 0..15
    int lb_n = (t & 15) << 2;   // 0..60
    const float* Aptr = A + (size_t)(bm + la_m) * K + la_q;
    const float* Bptr = Bw + (size_t)lb_k * N + bn + lb_n;
    float acc[4][4];
#pragma unroll
    for (int i = 0; i < 4; i++)
#pragma unroll
        for (int j = 0; j < 4; j++) acc[i][j] = 0.f;

    for (int k0 = 0; k0 < K; k0 += 16) {
        float4 av = *(const float4*)(Aptr + k0);
        float4 bv = *(const float4*)(Bptr + (size_t)k0 * N);
        __syncthreads();
        sA[la_q + 0][la_m] = av.x;
        sA[la_q + 1][la_m] = av.y;
        sA[la_q + 2][la_m] = av.z;
        sA[la_q + 3][la_m] = av.w;
        *(float4*)&sB[lb_k][lb_n] = bv;
        __syncthreads();
#pragma unroll
        for (int kk = 0; kk < 16; kk++) {
            float a0 = sA[kk][(ty << 2) + 0], a1 = sA[kk][(ty << 2) + 1];
            float a2 = sA[kk][(ty << 2) + 2], a3 = sA[kk][(ty << 2) + 3];
            float b0 = sB[kk][(tx << 2) + 0], b1 = sB[kk][(tx << 2) + 1];
            float b2 = sB[kk][(tx << 2) + 2], b3 = sB[kk][(tx << 2) + 3];
            acc[0][0] += a0 * b0; acc[0][1] += a0 * b1; acc[0][2] += a0 * b2; acc[0][3] += a0 * b3;
            acc[1][0] += a1 * b0; acc[1][1] += a1 * b1; acc[1][2] += a1 * b2; acc[1][3] += a1 * b3;
            acc[2][0] += a2 * b0; acc[2][1] += a2 * b1; acc[2][2] += a2 * b2; acc[2][3] += a2 * b3;
            acc[3][0] += a3 * b0; acc[3][1] += a3 * b1; acc[3][2] += a3 * b2; acc[3][3] += a3 * b3;
        }
    }
#pragma unroll
    for (int i = 0; i < 4; i++) {
        int row = bm + (ty << 2) + i;
        float vals[4];
#pragma unroll
        for (int j = 0; j < 4; j++) {
            float val = acc[i][j] + bias[bn + (tx << 2) + j];
            vals[j] = (mode == 0) ? fmaxf(val, 0.f) : val / 0.1f;
        }
        float4 o; o.x = vals[0]; o.y = vals[1]; o.z = vals[2]; o.w = vals[3];
        *(float4*)(Co + (size_t)row * N + bn + (tx << 2)) = o;
    }
}

// ---------------- Sinkhorn: u_i = -LSE_j(A0_ij + v_j)   (one wave per row)
__global__ __launch_bounds__(256) void row_lse(
    const float* __restrict__ A0, const float* __restrict__ vv,
    float* __restrict__ uu)
{
    int wid = blockIdx.x * 4 + (threadIdx.x >> 6);   // global row over NB*NG
    int lane = threadIdx.x & 63;
    int b = wid >> 9;
    const float* row = A0 + (size_t)wid * NG;
    const float* vb = vv + (b << 9);
    float x[8];
    float m = -INFINITY;
#pragma unroll
    for (int e = 0; e < 8; e++) {
        int j = (e << 6) + lane;
        x[e] = row[j] + vb[j];
        m = fmaxf(m, x[e]);
    }
#pragma unroll
    for (int off = 1; off < 64; off <<= 1) m = fmaxf(m, __shfl_xor(m, off));
    float s = 0.f;
#pragma unroll
    for (int e = 0; e < 8; e++) s += expf(x[e] - m);
#pragma unroll
    for (int off = 1; off < 64; off <<= 1) s += __shfl_xor(s, off);
    if (lane == 0) uu[wid] = -(m + logf(s));
}

// ---------------- Sinkhorn col step stage A: partial online LSE over 64-row chunks
__global__ __launch_bounds__(256) void col_partial(
    const float* __restrict__ A0, const float* __restrict__ uu,
    float* __restrict__ pm, float* __restrict__ ps)
{
    int blk = blockIdx.x;          // NB * 2 * 8 = 512 blocks
    int b = blk >> 4;
    int cc = blk & 1;
    int rc = (blk >> 1) & 7;
    int j = (cc << 8) + threadIdx.x;
    const float* base = A0 + ((size_t)(b << 9) + (rc << 6)) * NG + j;
    const float* ub = uu + (b << 9) + (rc << 6);
    float m = -INFINITY, s = 0.f;
    for (int i = 0; i < 64; i++) {
        float x = base[(size_t)i * NG] + ub[i];
        if (x > m) { s = s * expf(m - x) + 1.f; m = x; }
        else s += expf(x - m);
    }
    int o = ((b << 3) + rc) * NG + j;
    pm[o] = m; ps[o] = s;
}

// ---------------- Sinkhorn col step stage B: combine 8 partials -> v_j
__global__ __launch_bounds__(256) void col_combine(
    const float* __restrict__ pm, const float* __restrict__ ps,
    float* __restrict__ vv)
{
    int tid = blockIdx.x * 256 + threadIdx.x;  // NB*NG
    int b = tid >> 9, j = tid & 511;
    float M = -INFINITY;
#pragma unroll
    for (int rc = 0; rc < 8; rc++) M = fmaxf(M, pm[((b << 3) + rc) * NG + j]);
    float S = 0.f;
#pragma unroll
    for (int rc = 0; rc < 8; rc++) {
        int o = ((b << 3) + rc) * NG + j;
        S += ps[o] * expf(pm[o] - M);
    }
    vv[tid] = -(M + logf(S));
}

// ======== DPP reduce networks (to lane 63) ========
#define DPP6_MAXF(x)                                                              \
    { int _t;                                                                     \
      _t = __builtin_amdgcn_update_dpp(__float_as_int(x), __float_as_int(x),      \
               0x111, 0xf, 0xf, false); x = fmaxf(x, __int_as_float(_t));         \
      _t = __builtin_amdgcn_update_dpp(__float_as_int(x), __float_as_int(x),      \
               0x112, 0xf, 0xf, false); x = fmaxf(x, __int_as_float(_t));         \
      _t = __builtin_amdgcn_update_dpp(__float_as_int(x), __float_as_int(x),      \
               0x114, 0xf, 0xf, false); x = fmaxf(x, __int_as_float(_t));         \
      _t = __builtin_amdgcn_update_dpp(__float_as_int(x), __float_as_int(x),      \
               0x118, 0xf, 0xf, false); x = fmaxf(x, __int_as_float(_t));         \
      _t = __builtin_amdgcn_update_dpp(__float_as_int(x), __float_as_int(x),      \
               0x142, 0xa, 0xf, false); x = fmaxf(x, __int_as_float(_t));         \
      _t = __builtin_amdgcn_update_dpp(__float_as_int(x), __float_as_int(x),      \
               0x143, 0xc, 0xf, false); x = fmaxf(x, __int_as_float(_t)); }

#define DPP6_MINI(x)                                                              \
    { int _t;                                                                     \
      _t = __builtin_amdgcn_update_dpp(x, x, 0x111, 0xf, 0xf, false);             \
      x = (x < _t) ? x : _t;                                                      \
      _t = __builtin_amdgcn_update_dpp(x, x, 0x112, 0xf, 0xf, false);             \
      x = (x < _t) ? x : _t;                                                      \
      _t = __builtin_amdgcn_update_dpp(x, x, 0x114, 0xf, 0xf, false);             \
      x = (x < _t) ? x : _t;                                                      \
      _t = __builtin_amdgcn_update_dpp(x, x, 0x118, 0xf, 0xf, false);             \
      x = (x < _t) ? x : _t;                                                      \
      _t = __builtin_amdgcn_update_dpp(x, x, 0x142, 0xa, 0xf, false);             \
      x = (x < _t) ? x : _t;                                                      \
      _t = __builtin_amdgcn_update_dpp(x, x, 0x143, 0xc, 0xf, false);             \
      x = (x < _t) ? x : _t; }

// ---------------- P = exp((A0+u)+v) + per-row TOP-2 argmax (val desc, col asc).
// One wave per row; grid-wide. Memory-bound; the second reduce is free VALU.
__global__ __launch_bounds__(256) void p_rowmax(
    const float* __restrict__ A0, const float* __restrict__ uu,
    const float* __restrict__ vv, float* __restrict__ P,
    float* __restrict__ rbV, int* __restrict__ rbC,
    float* __restrict__ rbV2, int* __restrict__ rbC2)
{
    int wrow = blockIdx.x * 4 + (threadIdx.x >> 6);  // 0..16383
    int l = threadIdx.x & 63;
    int b = wrow >> 9;
    float ur = uu[wrow];
    const float* vb = vv + (b << 9);
    size_t ro = (size_t)wrow << 9;
    float4 a0 = *(const float4*)(A0 + ro + 4 * l);
    float4 a1 = *(const float4*)(A0 + ro + 256 + 4 * l);
    float4 v0 = *(const float4*)(vb + 4 * l);
    float4 v1 = *(const float4*)(vb + 256 + 4 * l);
    float p0 = expf(a0.x + ur + v0.x);
    float p1 = expf(a0.y + ur + v0.y);
    float p2 = expf(a0.z + ur + v0.z);
    float p3 = expf(a0.w + ur + v0.w);
    float p4 = expf(a1.x + ur + v1.x);
    float p5 = expf(a1.y + ur + v1.y);
    float p6 = expf(a1.z + ur + v1.z);
    float p7 = expf(a1.w + ur + v1.w);
    float4 o0; o0.x = p0; o0.y = p1; o0.z = p2; o0.w = p3;
    float4 o1; o1.x = p4; o1.y = p5; o1.z = p6; o1.w = p7;
    *(float4*)(P + ro + 4 * l) = o0;
    *(float4*)(P + ro + 256 + 4 * l) = o1;
    int cb = 4 * l;
    // ---- top-1 ----
    float mv = fmaxf(fmaxf(fmaxf(p0, p1), fmaxf(p2, p3)),
                     fmaxf(fmaxf(p4, p5), fmaxf(p6, p7)));
    int f = 0x7FFFFFFF;
    f = (p7 == mv) ? 256 + cb + 3 : f;
    f = (p6 == mv) ? 256 + cb + 2 : f;
    f = (p5 == mv) ? 256 + cb + 1 : f;
    f = (p4 == mv) ? 256 + cb + 0 : f;
    f = (p3 == mv) ? cb + 3 : f;
    f = (p2 == mv) ? cb + 2 : f;
    f = (p1 == mv) ? cb + 1 : f;
    f = (p0 == mv) ? cb + 0 : f;
    float g = mv;
    DPP6_MAXF(g)
    int gi = __builtin_amdgcn_readlane(__float_as_int(g), 63);
    float gm = __int_as_float(gi);
    int fs = (mv == gm) ? f : 0x7FFFFFFF;
    DPP6_MINI(fs)
    int c1 = __builtin_amdgcn_readlane(fs, 63);
    // ---- remove winner, top-2 ----
    float r0 = (cb + 0 == c1) ? -1.f : p0;
    float r1 = (cb + 1 == c1) ? -1.f : p1;
    float r2 = (cb + 2 == c1) ? -1.f : p2;
    float r3 = (cb + 3 == c1) ? -1.f : p3;
    float r4 = (256 + cb + 0 == c1) ? -1.f : p4;
    float r5 = (256 + cb + 1 == c1) ? -1.f : p5;
    float r6 = (256 + cb + 2 == c1) ? -1.f : p6;
    float r7 = (256 + cb + 3 == c1) ? -1.f : p7;
    float mv2 = fmaxf(fmaxf(fmaxf(r0, r1), fmaxf(r2, r3)),
                      fmaxf(fmaxf(r4, r5), fmaxf(r6, r7)));
    int f2 = 0x7FFFFFFF;
    f2 = (r7 == mv2) ? 256 + cb + 3 : f2;
    f2 = (r6 == mv2) ? 256 + cb + 2 : f2;
    f2 = (r5 == mv2) ? 256 + cb + 1 : f2;
    f2 = (r4 == mv2) ? 256 + cb + 0 : f2;
    f2 = (r3 == mv2) ? cb + 3 : f2;
    f2 = (r2 == mv2) ? cb + 2 : f2;
    f2 = (r1 == mv2) ? cb + 1 : f2;
    f2 = (r0 == mv2) ? cb + 0 : f2;
    float g2 = mv2;
    DPP6_MAXF(g2)
    int gi2 = __builtin_amdgcn_readlane(__float_as_int(g2), 63);
    float gm2 = __int_as_float(gi2);
    int fs2 = (mv2 == gm2) ? f2 : 0x7FFFFFFF;
    DPP6_MINI(fs2)
    if (l == 63) {
        rbV[wrow] = gm;  rbC[wrow] = c1;
        rbV2[wrow] = gm2; rbC2[wrow] = fs2;
    }
}

// ---------------- Greedy assignment: 1 wave per batch, no barriers, no LDS.
// Lane l owns rows 8l..8l+7 with TOP-2 cached candidates (rv/rf primary,
// sv/sf secondary; sv<0 = invalid). Eager invalidation keeps secondaries
// pointing only at free cols, so promotion is always legal. Cols 4l..4l+3 and
// 256+4l..+3 owned via free8. Exactly replicates repeated masked flat-argmax
// (ties: lowest r*G+c).
__global__ __launch_bounds__(64) void greedy5(
    const float* __restrict__ P,
    const float* __restrict__ rbV, const int* __restrict__ rbC,
    const float* __restrict__ rbV2, const int* __restrict__ rbC2,
    int* __restrict__ permInt)
{
    int b = blockIdx.x;
    int l = threadIdx.x;
    const float* Pb = P + (size_t)b * NG * NG;

    float rv[8]; int rf[8];
    float sv[8]; int sf[8];
    {
        const float* rvp = rbV + (b << 9) + 8 * l;
        const int*   rcp = rbC + (b << 9) + 8 * l;
        const float* svp = rbV2 + (b << 9) + 8 * l;
        const int*   scp = rbC2 + (b << 9) + 8 * l;
        float4 va = *(const float4*)(rvp);
        float4 vb = *(const float4*)(rvp + 4);
        int4 ca = *(const int4*)(rcp);
        int4 cb = *(const int4*)(rcp + 4);
        float4 wa = *(const float4*)(svp);
        float4 wb = *(const float4*)(svp + 4);
        int4 da = *(const int4*)(scp);
        int4 db = *(const int4*)(scp + 4);
        int base = (8 * l) << 9;
        rv[0] = va.x; rf[0] = (base + (0 << 9)) | ca.x;
        rv[1] = va.y; rf[1] = (base + (1 << 9)) | ca.y;
        rv[2] = va.z; rf[2] = (base + (2 << 9)) | ca.z;
        rv[3] = va.w; rf[3] = (base + (3 << 9)) | ca.w;
        rv[4] = vb.x; rf[4] = (base + (4 << 9)) | cb.x;
        rv[5] = vb.y; rf[5] = (base + (5 << 9)) | cb.y;
        rv[6] = vb.z; rf[6] = (base + (6 << 9)) | cb.z;
        rv[7] = vb.w; rf[7] = (base + (7 << 9)) | cb.w;
        sv[0] = wa.x; sf[0] = (base + (0 << 9)) | da.x;
        sv[1] = wa.y; sf[1] = (base + (1 << 9)) | da.y;
        sv[2] = wa.z; sf[2] = (base + (2 << 9)) | da.z;
        sv[3] = wa.w; sf[3] = (base + (3 << 9)) | da.w;
        sv[4] = wb.x; sf[4] = (base + (4 << 9)) | db.x;
        sv[5] = wb.y; sf[5] = (base + (5 << 9)) | db.y;
        sv[6] = wb.z; sf[6] = (base + (6 << 9)) | db.z;
        sv[7] = wb.w; sf[7] = (base + (7 << 9)) | db.w;
    }
    unsigned int free8 = 0xFF;

    for (int step = 0; step < NG; ++step) {
        // local best over my 8 rows (desc chain -> lowest k = lowest flat on tie)
        float mv = fmaxf(fmaxf(fmaxf(rv[0], rv[1]), fmaxf(rv[2], rv[3])),
                         fmaxf(fmaxf(rv[4], rv[5]), fmaxf(rv[6], rv[7])));
        int f = 0x7FFFFFFF;
        f = (rv[7] == mv) ? rf[7] : f;
        f = (rv[6] == mv) ? rf[6] : f;
        f = (rv[5] == mv) ? rf[5] : f;
        f = (rv[4] == mv) ? rf[4] : f;
        f = (rv[3] == mv) ? rf[3] : f;
        f = (rv[2] == mv) ? rf[2] : f;
        f = (rv[1] == mv) ? rf[1] : f;
        f = (rv[0] == mv) ? rf[0] : f;
        // wave max; tie -> lowest tied lane (its rows are the lowest flats)
        float g = mv;
        DPP6_MAXF(g)
        int gi = __builtin_amdgcn_readlane(__float_as_int(g), 63);
        float gm = __int_as_float(gi);
        unsigned long long tb = __ballot(mv == gm);
        int tl = __ffsll(tb) - 1;
        int bestf = __builtin_amdgcn_readlane(f, tl);
        int r = bestf >> 9, c = bestf & 511;
        if (l == 0) permInt[(b << 9) + r] = c;
        // take column c
        {
            int owner = (c & 255) >> 2;
            int bit = (c & 3) | ((c & 256) >> 6);
            if (l == owner) free8 &= ~(1u << bit);
        }
        // per-k bookkeeping: retire taken row; promote/flag rows hit on primary;
        // eagerly invalidate secondaries pointing at c
        int needRescan = 0;
        int rowbase = l << 3;
#pragma unroll
        for (int k = 0; k < 8; k++) {
            bool taken = (rowbase + k) == r;
            bool hit1 = (rv[k] >= 0.f) && (((rf[k] ^ c) & 511) == 0);
            if (taken) {
                rv[k] = -1.f; sv[k] = -1.f;
            } else if (hit1) {
                if (sv[k] >= 0.f) { rv[k] = sv[k]; rf[k] = sf[k]; sv[k] = -1.f; }
                else needRescan |= 1 << k;
            }
            if (sv[k] >= 0.f && ((sf[k] ^ c) & 511) == 0) sv[k] = -1.f;
        }
        // rescans: rare (both candidates dead). Full-wave top-2 refill.
        unsigned long long dd = __ballot(needRescan != 0);
        while (dd) {
            int src = __ffsll(dd) - 1; dd &= dd - 1;
            int dmk = __builtin_amdgcn_readlane(needRescan, src);
            while (dmk) {
                int kk = __ffs(dmk) - 1; dmk &= dmk - 1;
                int rr = (src << 3) + kk;
                const float* rowp = Pb + ((size_t)rr << 9);
                float4 x0 = *(const float4*)(rowp + 4 * l);
                float4 x1 = *(const float4*)(rowp + 256 + 4 * l);
                float q0 = (free8 & 1u)   ? x0.x : -1.0f;
                float q1 = (free8 & 2u)   ? x0.y : -1.0f;
                float q2 = (free8 & 4u)   ? x0.z : -1.0f;
                float q3 = (free8 & 8u)   ? x0.w : -1.0f;
                float q4 = (free8 & 16u)  ? x1.x : -1.0f;
                float q5 = (free8 & 32u)  ? x1.y : -1.0f;
                float q6 = (free8 & 64u)  ? x1.z : -1.0f;
                float q7 = (free8 & 128u) ? x1.w : -1.0f;
                int sb = rr << 9;
                int cb = 4 * l;
                // top-1
                float lm = fmaxf(fmaxf(fmaxf(q0, q1), fmaxf(q2, q3)),
                                 fmaxf(fmaxf(q4, q5), fmaxf(q6, q7)));
                int lf = 0x7FFFFFFF;
                lf = (q7 == lm) ? sb + 256 + cb + 3 : lf;
                lf = (q6 == lm) ? sb + 256 + cb + 2 : lf;
                lf = (q5 == lm) ? sb + 256 + cb + 1 : lf;
                lf = (q4 == lm) ? sb + 256 + cb + 0 : lf;
                lf = (q3 == lm) ? sb + cb + 3 : lf;
                lf = (q2 == lm) ? sb + cb + 2 : lf;
                lf = (q1 == lm) ? sb + cb + 1 : lf;
                lf = (q0 == lm) ? sb + cb + 0 : lf;
                float gg = lm;
                DPP6_MAXF(gg)
                int ggi = __builtin_amdgcn_readlane(__float_as_int(gg), 63);
                float g1 = __int_as_float(ggi);
                int t1 = (lm == g1) ? lf : 0x7FFFFFFF;
                DPP6_MINI(t1)
                int gf1 = __builtin_amdgcn_readlane(t1, 63);
                // remove winner col locally
                int wc = gf1 & 511;
                q0 = (cb + 0 == wc) ? -1.f : q0;
                q1 = (cb + 1 == wc) ? -1.f : q1;
                q2 = (cb + 2 == wc) ? -1.f : q2;
                q3 = (cb + 3 == wc) ? -1.f : q3;
                q4 = (256 + cb + 0 == wc) ? -1.f : q4;
                q5 = (256 + cb + 1 == wc) ? -1.f : q5;
                q6 = (256 + cb + 2 == wc) ? -1.f : q6;
                q7 = (256 + cb + 3 == wc) ? -1.f : q7;
                // top-2
                float lm2 = fmaxf(fmaxf(fmaxf(q0, q1), fmaxf(q2, q3)),
                                  fmaxf(fmaxf(q4, q5), fmaxf(q6, q7)));
                int lf2 = 0x7FFFFFFF;
                lf2 = (q7 == lm2) ? sb + 256 + cb + 3 : lf2;
                lf2 = (q6 == lm2) ? sb + 256 + cb + 2 : lf2;
                lf2 = (q5 == lm2) ? sb + 256 + cb + 1 : lf2;
                lf2 = (q4 == lm2) ? sb + 256 + cb + 0 : lf2;
                lf2 = (q3 == lm2) ? sb + cb + 3 : lf2;
                lf2 = (q2 == lm2) ? sb + cb + 2 : lf2;
                lf2 = (q1 == lm2) ? sb + cb + 1 : lf2;
                lf2 = (q0 == lm2) ? sb + cb + 0 : lf2;
                float gg2 = lm2;
                DPP6_MAXF(gg2)
                int ggi2 = __builtin_amdgcn_readlane(__float_as_int(gg2), 63);
                float g2v = __int_as_float(ggi2);
                int t2 = (lm2 == g2v) ? lf2 : 0x7FFFFFFF;
                DPP6_MINI(t2)
                int gf2 = __builtin_amdgcn_readlane(t2, 63);
                if (l == src) {
                    switch (kk) {
                        case 0: rv[0] = g1; rf[0] = gf1; sv[0] = g2v; sf[0] = gf2; break;
                        case 1: rv[1] = g1; rf[1] = gf1; sv[1] = g2v; sf[1] = gf2; break;
                        case 2: rv[2] = g1; rf[2] = gf1; sv[2] = g2v; sf[2] = gf2; break;
                        case 3: rv[3] = g1; rf[3] = gf1; sv[3] = g2v; sf[3] = gf2; break;
                        case 4: rv[4] = g1; rf[4] = gf1; sv[4] = g2v; sf[4] = gf2; break;
                        case 5: rv[5] = g1; rf[5] = gf1; sv[5] = g2v; sf[5] = gf2; break;
                        case 6: rv[6] = g1; rf[6] = gf1; sv[6] = g2v; sf[6] = gf2; break;
                        case 7: rv[7] = g1; rf[7] = gf1; sv[7] = g2v; sf[7] = gf2; break;
                    }
                }
            }
        }
    }
}

// ---------------- apply permutation: out[b][perm[r]] = in[b][r]
__global__ void scatter_coords(const float* __restrict__ src,
    const int* __restrict__ perm, float* __restrict__ dst,
    float* __restrict__ permF)
{
    int tid = blockIdx.x * 256 + threadIdx.x;
    if (tid >= NB * NG) return;
    int b = tid >> 9;
    int p = perm[tid];
    permF[tid] = (float)p;
    size_t so = (size_t)tid * 3;
    size_t dd = ((size_t)(b << 9) + p) * 3;
    dst[dd] = src[so]; dst[dd + 1] = src[so + 1]; dst[dd + 2] = src[so + 2];
}

__global__ void scatter_feats(const float* __restrict__ src,
    const int* __restrict__ perm, float* __restrict__ dst)
{
    int tid = blockIdx.x * 256 + threadIdx.x;   // NB*NG*96 float4s
    int rc = tid / 96;
    int q = tid - rc * 96;
    int b = rc >> 9;
    int p = perm[rc];
    const float4* s4 = (const float4*)(src + (size_t)rc * NC);
    float4* d4 = (float4*)(dst + ((size_t)(b << 9) + p) * NC);
    d4[q] = s4[q];
}

extern "C" void kernel_launch(void* const* d_in, const int* in_sizes, int n_in,
                              void* d_out, int out_size, void* d_ws, size_t ws_size,
                              hipStream_t stream)
{
    const float* coords = (const float*)d_in[0];
    const float* feats  = (const float*)d_in[1];
    const float* W1 = (const float*)d_in[2];
    const float* b1 = (const float*)d_in[3];
    const float* W2 = (const float*)d_in[4];
    const float* b2 = (const float*)d_in[5];

    float* out = (float*)d_out;
    float* outCoords = out;
    float* outFeats  = out + (size_t)NB * NG * 3;
    float* outPerm   = out + (size_t)NB * NG * 3 + (size_t)NB * NG * NC;

    float* ws = (float*)d_ws;
    float* h   = ws;                                  // 16384*768 (reused as P later)
    float* A0  = h + (size_t)NB * NG * NH;            // 16384*512  (= scores/TAU)
    float* u   = A0 + (size_t)NB * NG * NG;           // 16384
    float* v   = u + NB * NG;                         // 16384
    float* pm  = v + NB * NG;                         // 32*8*512
    float* ps  = pm + NB * 8 * NG;                    // 32*8*512
    float* rbV = ps + NB * 8 * NG;                    // 16384
    int* rbC   = (int*)(rbV + NB * NG);               // 16384
    float* rbV2 = (float*)(rbC + NB * NG);            // 16384
    int* rbC2  = (int*)(rbV2 + NB * NG);              // 16384
    int* permInt = (int*)(rbC2 + NB * NG);            // 16384

    const int M = NB * NG;  // 16384

    // h = relu(feats @ W1 + b1)
    gemm_bias<<<dim3((M / 64) * (NH / 64)), 256, 0, stream>>>(
        feats, W1, b1, h, M, NH, NC, 0);
    // A0 = (h @ W2 + b2) / TAU
    gemm_bias<<<dim3((M / 64) * (NG / 64)), 256, 0, stream>>>(
        h, W2, b2, A0, M, NG, NH, 1);

    hipMemsetAsync(v, 0, (size_t)NB * NG * sizeof(float), stream);

    for (int it = 0; it < 10; ++it) {
        row_lse<<<dim3(M / 4), 256, 0, stream>>>(A0, v, u);
        col_partial<<<dim3(NB * 16), 256, 0, stream>>>(A0, u, pm, ps);
        col_combine<<<dim3(M / 256), 256, 0, stream>>>(pm, ps, v);
    }

    // P = exp(A0+u+v) + per-row top-2 argmax (grid-wide, memory-bound)
    float* P = h;
    p_rowmax<<<dim3(M / 4), 256, 0, stream>>>(A0, u, v, P, rbV, rbC, rbV2, rbC2);

    greedy5<<<dim3(NB), 64, 0, stream>>>(P, rbV, rbC, rbV2, rbC2, permInt);

    scatter_coords<<<dim3((NB * NG + 255) / 256), 256, 0, stream>>>(coords, permInt, outCoords, outPerm);
    scatter_feats<<<dim3((NB * NG * 96) / 256), 256, 0, stream>>>(feats, permInt, outFeats);
}

// Round 7
// 977.849 us; speedup vs baseline: 1.3643x; 1.3643x over previous
//
#include <hip/hip_runtime.h>
#include <math.h>

#define NB 32
#define NG 512
#define NC 384
#define NH 768

// ---------------- GEMM: C = op(A @ Bw + bias). 128x128 tile, 256 threads,
// 8x8 per thread (split rows {4ty+i, 64+4ty+i}, cols {4tx+j, 64+4tx+j}).
// K-accumulation order identical to the previous kernel (k0 += 16, kk 0..15
// ascending) -> bit-identical outputs. mode 0: relu, mode 1: /0.1 (scores/TAU)
__global__ __launch_bounds__(256, 2) void gemm_bias_128(
    const float* __restrict__ A, const float* __restrict__ Bw,
    const float* __restrict__ bias, float* __restrict__ Co,
    int M, int N, int K, int mode)
{
    __shared__ float sA[16][128];
    __shared__ float sB[16][128];
    int ntiles = N >> 7;
    int bm = (blockIdx.x / ntiles) << 7;
    int bn = (blockIdx.x % ntiles) << 7;
    int t = threadIdx.x;
    int tx = t & 15, ty = t >> 4;
    // A staging: rows tr and 64+tr, k chunk 4*tc
    int tr = t >> 2, tc = t & 3;
    const float* Aptr0 = A + (size_t)(bm + tr) * K + 4 * tc;
    const float* Aptr1 = A + (size_t)(bm + 64 + tr) * K + 4 * tc;
    // B staging: row kb, cols 4*nc and 64+4*nc
    int kb = t >> 4, nc = t & 15;
    const float* BptrL = Bw + (size_t)kb * N + bn + 4 * nc;
    const float* BptrH = Bw + (size_t)kb * N + bn + 64 + 4 * nc;

    float acc[8][8];
#pragma unroll
    for (int i = 0; i < 8; i++)
#pragma unroll
        for (int j = 0; j < 8; j++) acc[i][j] = 0.f;

    for (int k0 = 0; k0 < K; k0 += 16) {
        float4 a0 = *(const float4*)(Aptr0 + k0);
        float4 a1 = *(const float4*)(Aptr1 + k0);
        float4 b0 = *(const float4*)(BptrL + (size_t)k0 * N);
        float4 b1 = *(const float4*)(BptrH + (size_t)k0 * N);
        __syncthreads();
        sA[4 * tc + 0][tr] = a0.x;
        sA[4 * tc + 1][tr] = a0.y;
        sA[4 * tc + 2][tr] = a0.z;
        sA[4 * tc + 3][tr] = a0.w;
        sA[4 * tc + 0][64 + tr] = a1.x;
        sA[4 * tc + 1][64 + tr] = a1.y;
        sA[4 * tc + 2][64 + tr] = a1.z;
        sA[4 * tc + 3][64 + tr] = a1.w;
        *(float4*)&sB[kb][4 * nc] = b0;
        *(float4*)&sB[kb][64 + 4 * nc] = b1;
        __syncthreads();
#pragma unroll
        for (int kk = 0; kk < 16; kk++) {
            float4 aL = *(const float4*)&sA[kk][4 * ty];
            float4 aH = *(const float4*)&sA[kk][64 + 4 * ty];
            float4 bL = *(const float4*)&sB[kk][4 * tx];
            float4 bH = *(const float4*)&sB[kk][64 + 4 * tx];
            float av[8] = { aL.x, aL.y, aL.z, aL.w, aH.x, aH.y, aH.z, aH.w };
            float bv[8] = { bL.x, bL.y, bL.z, bL.w, bH.x, bH.y, bH.z, bH.w };
#pragma unroll
            for (int i = 0; i < 8; i++)
#pragma unroll
                for (int j = 0; j < 8; j++) acc[i][j] += av[i] * bv[j];
        }
    }

    float4 blo = *(const float4*)(bias + bn + 4 * tx);
    float4 bhi = *(const float4*)(bias + bn + 64 + 4 * tx);
    float bb[8] = { blo.x, blo.y, blo.z, blo.w, bhi.x, bhi.y, bhi.z, bhi.w };
#pragma unroll
    for (int i = 0; i < 8; i++) {
        int row = bm + ((i < 4) ? (4 * ty + i) : (64 + 4 * ty + i - 4));
        float vals[8];
#pragma unroll
        for (int j = 0; j < 8; j++) {
            float val = acc[i][j] + bb[j];
            vals[j] = (mode == 0) ? fmaxf(val, 0.f) : val / 0.1f;
        }
        float4 oL; oL.x = vals[0]; oL.y = vals[1]; oL.z = vals[2]; oL.w = vals[3];
        float4 oH; oH.x = vals[4]; oH.y = vals[5]; oH.z = vals[6]; oH.w = vals[7];
        *(float4*)(Co + (size_t)row * N + bn + 4 * tx) = oL;
        *(float4*)(Co + (size_t)row * N + bn + 64 + 4 * tx) = oH;
    }
}

// ---------------- Sinkhorn: u_i = -LSE_j(A0_ij + v_j)   (one wave per row)
__global__ __launch_bounds__(256) void row_lse(
    const float* __restrict__ A0, const float* __restrict__ vv,
    float* __restrict__ uu)
{
    int wid = blockIdx.x * 4 + (threadIdx.x >> 6);   // global row over NB*NG
    int lane = threadIdx.x & 63;
    int b = wid >> 9;
    const float* row = A0 + (size_t)wid * NG;
    const float* vb = vv + (b << 9);
    float x[8];
    float m = -INFINITY;
#pragma unroll
    for (int e = 0; e < 8; e++) {
        int j = (e << 6) + lane;
        x[e] = row[j] + vb[j];
        m = fmaxf(m, x[e]);
    }
#pragma unroll
    for (int off = 1; off < 64; off <<= 1) m = fmaxf(m, __shfl_xor(m, off));
    float s = 0.f;
#pragma unroll
    for (int e = 0; e < 8; e++) s += expf(x[e] - m);
#pragma unroll
    for (int off = 1; off < 64; off <<= 1) s += __shfl_xor(s, off);
    if (lane == 0) uu[wid] = -(m + logf(s));
}

// ---------------- Sinkhorn col step stage A: partial online LSE over 64-row chunks
__global__ __launch_bounds__(256) void col_partial(
    const float* __restrict__ A0, const float* __restrict__ uu,
    float* __restrict__ pm, float* __restrict__ ps)
{
    int blk = blockIdx.x;          // NB * 2 * 8 = 512 blocks
    int b = blk >> 4;
    int cc = blk & 1;
    int rc = (blk >> 1) & 7;
    int j = (cc << 8) + threadIdx.x;
    const float* base = A0 + ((size_t)(b << 9) + (rc << 6)) * NG + j;
    const float* ub = uu + (b << 9) + (rc << 6);
    float m = -INFINITY, s = 0.f;
    for (int i = 0; i < 64; i++) {
        float x = base[(size_t)i * NG] + ub[i];
        if (x > m) { s = s * expf(m - x) + 1.f; m = x; }
        else s += expf(x - m);
    }
    int o = ((b << 3) + rc) * NG + j;
    pm[o] = m; ps[o] = s;
}

// ---------------- Sinkhorn col step stage B: combine 8 partials -> v_j
__global__ __launch_bounds__(256) void col_combine(
    const float* __restrict__ pm, const float* __restrict__ ps,
    float* __restrict__ vv)
{
    int tid = blockIdx.x * 256 + threadIdx.x;  // NB*NG
    int b = tid >> 9, j = tid & 511;
    float M = -INFINITY;
#pragma unroll
    for (int rc = 0; rc < 8; rc++) M = fmaxf(M, pm[((b << 3) + rc) * NG + j]);
    float S = 0.f;
#pragma unroll
    for (int rc = 0; rc < 8; rc++) {
        int o = ((b << 3) + rc) * NG + j;
        S += ps[o] * expf(pm[o] - M);
    }
    vv[tid] = -(M + logf(S));
}

// ======== DPP max reduce to lane 63 (pure VALU) ========
#define DPP6_MAXF(x)                                                              \
    { int _t;                                                                     \
      _t = __builtin_amdgcn_update_dpp(__float_as_int(x), __float_as_int(x),      \
               0x111, 0xf, 0xf, false); x = fmaxf(x, __int_as_float(_t));         \
      _t = __builtin_amdgcn_update_dpp(__float_as_int(x), __float_as_int(x),      \
               0x112, 0xf, 0xf, false); x = fmaxf(x, __int_as_float(_t));         \
      _t = __builtin_amdgcn_update_dpp(__float_as_int(x), __float_as_int(x),      \
               0x114, 0xf, 0xf, false); x = fmaxf(x, __int_as_float(_t));         \
      _t = __builtin_amdgcn_update_dpp(__float_as_int(x), __float_as_int(x),      \
               0x118, 0xf, 0xf, false); x = fmaxf(x, __int_as_float(_t));         \
      _t = __builtin_amdgcn_update_dpp(__float_as_int(x), __float_as_int(x),      \
               0x142, 0xa, 0xf, false); x = fmaxf(x, __int_as_float(_t));         \
      _t = __builtin_amdgcn_update_dpp(__float_as_int(x), __float_as_int(x),      \
               0x143, 0xc, 0xf, false); x = fmaxf(x, __int_as_float(_t)); }

// ---------------- P = exp((A0+u)+v) + per-row argmax (val desc, col asc).
// Lane l covers cols 8l..8l+7 (col-monotone in lane -> tie-break = lowest
// tied lane via ballot; within lane, desc select chain keeps lowest col).
__global__ __launch_bounds__(256) void p_rowmax(
    const float* __restrict__ A0, const float* __restrict__ uu,
    const float* __restrict__ vv, float* __restrict__ P,
    float* __restrict__ rbV, int* __restrict__ rbC)
{
    int wrow = blockIdx.x * 4 + (threadIdx.x >> 6);  // 0..16383
    int l = threadIdx.x & 63;
    int b = wrow >> 9;
    float ur = uu[wrow];
    const float* vb = vv + (b << 9);
    size_t ro = (size_t)wrow << 9;
    float4 a0 = *(const float4*)(A0 + ro + 8 * l);
    float4 a1 = *(const float4*)(A0 + ro + 8 * l + 4);
    float4 v0 = *(const float4*)(vb + 8 * l);
    float4 v1 = *(const float4*)(vb + 8 * l + 4);
    float p0 = expf(a0.x + ur + v0.x);
    float p1 = expf(a0.y + ur + v0.y);
    float p2 = expf(a0.z + ur + v0.z);
    float p3 = expf(a0.w + ur + v0.w);
    float p4 = expf(a1.x + ur + v1.x);
    float p5 = expf(a1.y + ur + v1.y);
    float p6 = expf(a1.z + ur + v1.z);
    float p7 = expf(a1.w + ur + v1.w);
    float4 o0; o0.x = p0; o0.y = p1; o0.z = p2; o0.w = p3;
    float4 o1; o1.x = p4; o1.y = p5; o1.z = p6; o1.w = p7;
    *(float4*)(P + ro + 8 * l) = o0;
    *(float4*)(P + ro + 8 * l + 4) = o1;
    float mv = fmaxf(fmaxf(fmaxf(p0, p1), fmaxf(p2, p3)),
                     fmaxf(fmaxf(p4, p5), fmaxf(p6, p7)));
    int cb = 8 * l;
    int f = 0x7FFFFFFF;
    f = (p7 == mv) ? cb + 7 : f;
    f = (p6 == mv) ? cb + 6 : f;
    f = (p5 == mv) ? cb + 5 : f;
    f = (p4 == mv) ? cb + 4 : f;
    f = (p3 == mv) ? cb + 3 : f;
    f = (p2 == mv) ? cb + 2 : f;
    f = (p1 == mv) ? cb + 1 : f;
    f = (p0 == mv) ? cb + 0 : f;
    float g = mv;
    DPP6_MAXF(g)
    int gi = __builtin_amdgcn_readlane(__float_as_int(g), 63);
    float gm = __int_as_float(gi);
    unsigned long long tb = __ballot(mv == gm);
    int tl = __ffsll(tb) - 1;
    int bestc = __builtin_amdgcn_readlane(f, tl);
    if (l == 0) { rbV[wrow] = gm; rbC[wrow] = bestc; }
}

// ---------------- Greedy assignment: 1 wave per batch, no barriers, no LDS.
// Lane l owns rows 8l..8l+7 (rv=val, rf=(row<<9)|col; retired rows keep their
// assigned col in rf for the final dump) and cols 8l..8l+7 (free8 bit k =
// col 8l+k). Dirty-row rescans are 2-deep software-pipelined. Exactly
// replicates repeated masked flat-argmax (ties: lowest r*G+c).
__global__ __launch_bounds__(64) void greedy6(
    const float* __restrict__ P, const float* __restrict__ rbV,
    const int* __restrict__ rbC, int* __restrict__ permInt)
{
    int b = blockIdx.x;
    int l = threadIdx.x;
    const float* Pb = P + (size_t)b * NG * NG;

    float rv[8]; int rf[8];
    {
        const float* rvp = rbV + (b << 9) + 8 * l;
        const int*   rcp = rbC + (b << 9) + 8 * l;
        float4 va = *(const float4*)(rvp);
        float4 vb = *(const float4*)(rvp + 4);
        int4 ca = *(const int4*)(rcp);
        int4 cb = *(const int4*)(rcp + 4);
        int base = (8 * l) << 9;
        rv[0] = va.x; rf[0] = (base + (0 << 9)) | ca.x;
        rv[1] = va.y; rf[1] = (base + (1 << 9)) | ca.y;
        rv[2] = va.z; rf[2] = (base + (2 << 9)) | ca.z;
        rv[3] = va.w; rf[3] = (base + (3 << 9)) | ca.w;
        rv[4] = vb.x; rf[4] = (base + (4 << 9)) | cb.x;
        rv[5] = vb.y; rf[5] = (base + (5 << 9)) | cb.y;
        rv[6] = vb.z; rf[6] = (base + (6 << 9)) | cb.z;
        rv[7] = vb.w; rf[7] = (base + (7 << 9)) | cb.w;
    }
    unsigned int free8 = 0xFF;

    for (int step = 0; step < NG; ++step) {
        // local best over my 8 rows (desc chain -> lowest k = lowest flat)
        float mv = fmaxf(fmaxf(fmaxf(rv[0], rv[1]), fmaxf(rv[2], rv[3])),
                         fmaxf(fmaxf(rv[4], rv[5]), fmaxf(rv[6], rv[7])));
        int f = 0x7FFFFFFF;
        f = (rv[7] == mv) ? rf[7] : f;
        f = (rv[6] == mv) ? rf[6] : f;
        f = (rv[5] == mv) ? rf[5] : f;
        f = (rv[4] == mv) ? rf[4] : f;
        f = (rv[3] == mv) ? rf[3] : f;
        f = (rv[2] == mv) ? rf[2] : f;
        f = (rv[1] == mv) ? rf[1] : f;
        f = (rv[0] == mv) ? rf[0] : f;
        // wave max; ties -> lowest tied lane (rows monotone in lane)
        float g = mv;
        DPP6_MAXF(g)
        int gi = __builtin_amdgcn_readlane(__float_as_int(g), 63);
        float gm = __int_as_float(gi);
        unsigned long long tb = __ballot(mv == gm);
        int tl = __ffsll(tb) - 1;
        int bestf = __builtin_amdgcn_readlane(f, tl);
        int r = bestf >> 9, c = bestf & 511;
        // take column c
        if (l == (c >> 3)) free8 &= ~(1u << (c & 7));
        // retire taken row + collect dirty rows (alive, cached col == c, not taken)
        int rl = r - (l << 3);
        int dmk = 0;
#pragma unroll
        for (int k = 0; k < 8; k++) {
            bool alive = rv[k] >= 0.f;
            bool cm = ((rf[k] ^ c) & 511) == 0;
            bool taken = (rl == k);
            if (taken) rv[k] = -1.f;
            dmk |= (alive && cm && !taken) ? (1 << k) : 0;
        }
        unsigned long long act = __ballot(dmk != 0);
        if (!act) continue;
        // ---- 2-deep pipelined rescans ----
        int srcA = __ffsll(act) - 1;
        int kkA = __ffs(__builtin_amdgcn_readlane(dmk, srcA)) - 1;
        if (l == srcA) dmk &= ~(1 << kkA);
        int rrA = (srcA << 3) + kkA;
        float4 xA0 = *(const float4*)(Pb + ((size_t)rrA << 9) + 8 * l);
        float4 xA1 = *(const float4*)(Pb + ((size_t)rrA << 9) + 8 * l + 4);
        for (;;) {
            act = __ballot(dmk != 0);
            bool haveB = act != 0;
            int srcB = 0, kkB = 0, rrB = 0;
            float4 xB0, xB1;
            if (haveB) {
                srcB = __ffsll(act) - 1;
                kkB = __ffs(__builtin_amdgcn_readlane(dmk, srcB)) - 1;
                if (l == srcB) dmk &= ~(1 << kkB);
                rrB = (srcB << 3) + kkB;
                xB0 = *(const float4*)(Pb + ((size_t)rrB << 9) + 8 * l);
                xB1 = *(const float4*)(Pb + ((size_t)rrB << 9) + 8 * l + 4);
            }
            // reduce A: masked row argmax over free cols
            float q0 = (free8 & 1u)   ? xA0.x : -1.0f;
            float q1 = (free8 & 2u)   ? xA0.y : -1.0f;
            float q2 = (free8 & 4u)   ? xA0.z : -1.0f;
            float q3 = (free8 & 8u)   ? xA0.w : -1.0f;
            float q4 = (free8 & 16u)  ? xA1.x : -1.0f;
            float q5 = (free8 & 32u)  ? xA1.y : -1.0f;
            float q6 = (free8 & 64u)  ? xA1.z : -1.0f;
            float q7 = (free8 & 128u) ? xA1.w : -1.0f;
            float lm = fmaxf(fmaxf(fmaxf(q0, q1), fmaxf(q2, q3)),
                             fmaxf(fmaxf(q4, q5), fmaxf(q6, q7)));
            int sb = (rrA << 9) + 8 * l;
            int lf = 0x7FFFFFFF;
            lf = (q7 == lm) ? sb + 7 : lf;
            lf = (q6 == lm) ? sb + 6 : lf;
            lf = (q5 == lm) ? sb + 5 : lf;
            lf = (q4 == lm) ? sb + 4 : lf;
            lf = (q3 == lm) ? sb + 3 : lf;
            lf = (q2 == lm) ? sb + 2 : lf;
            lf = (q1 == lm) ? sb + 1 : lf;
            lf = (q0 == lm) ? sb + 0 : lf;
            float gg = lm;
            DPP6_MAXF(gg)
            int ggi = __builtin_amdgcn_readlane(__float_as_int(gg), 63);
            float g1 = __int_as_float(ggi);
            unsigned long long tb2 = __ballot(lm == g1);
            int tl2 = __ffsll(tb2) - 1;
            int nf = __builtin_amdgcn_readlane(lf, tl2);
            if (l == srcA) {
                switch (kkA) {
                    case 0: rv[0] = g1; rf[0] = nf; break;
                    case 1: rv[1] = g1; rf[1] = nf; break;
                    case 2: rv[2] = g1; rf[2] = nf; break;
                    case 3: rv[3] = g1; rf[3] = nf; break;
                    case 4: rv[4] = g1; rf[4] = nf; break;
                    case 5: rv[5] = g1; rf[5] = nf; break;
                    case 6: rv[6] = g1; rf[6] = nf; break;
                    case 7: rv[7] = g1; rf[7] = nf; break;
                }
            }
            if (!haveB) break;
            srcA = srcB; kkA = kkB; rrA = rrB; xA0 = xB0; xA1 = xB1;
        }
    }
    // dump perm: retired rf[k] low 9 bits = assigned col of row 8l+k
    int4 o0; o0.x = rf[0] & 511; o0.y = rf[1] & 511; o0.z = rf[2] & 511; o0.w = rf[3] & 511;
    int4 o1; o1.x = rf[4] & 511; o1.y = rf[5] & 511; o1.z = rf[6] & 511; o1.w = rf[7] & 511;
    *(int4*)(permInt + (b << 9) + 8 * l) = o0;
    *(int4*)(permInt + (b << 9) + 8 * l + 4) = o1;
}

// ---------------- apply permutation: out[b][perm[r]] = in[b][r]
__global__ void scatter_coords(const float* __restrict__ src,
    const int* __restrict__ perm, float* __restrict__ dst,
    float* __restrict__ permF)
{
    int tid = blockIdx.x * 256 + threadIdx.x;
    if (tid >= NB * NG) return;
    int b = tid >> 9;
    int p = perm[tid];
    permF[tid] = (float)p;
    size_t so = (size_t)tid * 3;
    size_t dd = ((size_t)(b << 9) + p) * 3;
    dst[dd] = src[so]; dst[dd + 1] = src[so + 1]; dst[dd + 2] = src[so + 2];
}

__global__ void scatter_feats(const float* __restrict__ src,
    const int* __restrict__ perm, float* __restrict__ dst)
{
    int tid = blockIdx.x * 256 + threadIdx.x;   // NB*NG*96 float4s
    int rc = tid / 96;
    int q = tid - rc * 96;
    int b = rc >> 9;
    int p = perm[rc];
    const float4* s4 = (const float4*)(src + (size_t)rc * NC);
    float4* d4 = (float4*)(dst + ((size_t)(b << 9) + p) * NC);
    d4[q] = s4[q];
}

extern "C" void kernel_launch(void* const* d_in, const int* in_sizes, int n_in,
                              void* d_out, int out_size, void* d_ws, size_t ws_size,
                              hipStream_t stream)
{
    const float* coords = (const float*)d_in[0];
    const float* feats  = (const float*)d_in[1];
    const float* W1 = (const float*)d_in[2];
    const float* b1 = (const float*)d_in[3];
    const float* W2 = (const float*)d_in[4];
    const float* b2 = (const float*)d_in[5];

    float* out = (float*)d_out;
    float* outCoords = out;
    float* outFeats  = out + (size_t)NB * NG * 3;
    float* outPerm   = out + (size_t)NB * NG * 3 + (size_t)NB * NG * NC;

    float* ws = (float*)d_ws;
    float* h   = ws;                                  // 16384*768 (reused as P later)
    float* A0  = h + (size_t)NB * NG * NH;            // 16384*512  (= scores/TAU)
    float* u   = A0 + (size_t)NB * NG * NG;           // 16384
    float* v   = u + NB * NG;                         // 16384
    float* pm  = v + NB * NG;                         // 32*8*512
    float* ps  = pm + NB * 8 * NG;                    // 32*8*512
    float* rbV = ps + NB * 8 * NG;                    // 16384
    int* rbC   = (int*)(rbV + NB * NG);               // 16384
    int* permInt = (int*)(rbC + NB * NG);             // 16384

    const int M = NB * NG;  // 16384

    // h = relu(feats @ W1 + b1)
    gemm_bias_128<<<dim3((M / 128) * (NH / 128)), 256, 0, stream>>>(
        feats, W1, b1, h, M, NH, NC, 0);
    // A0 = (h @ W2 + b2) / TAU
    gemm_bias_128<<<dim3((M / 128) * (NG / 128)), 256, 0, stream>>>(
        h, W2, b2, A0, M, NG, NH, 1);

    hipMemsetAsync(v, 0, (size_t)NB * NG * sizeof(float), stream);

    for (int it = 0; it < 10; ++it) {
        row_lse<<<dim3(M / 4), 256, 0, stream>>>(A0, v, u);
        col_partial<<<dim3(NB * 16), 256, 0, stream>>>(A0, u, pm, ps);
        col_combine<<<dim3(M / 256), 256, 0, stream>>>(pm, ps, v);
    }

    // P = exp(A0+u+v) + per-row argmax (grid-wide, memory-bound)
    float* P = h;
    p_rowmax<<<dim3(M / 4), 256, 0, stream>>>(A0, u, v, P, rbV, rbC);

    greedy6<<<dim3(NB), 64, 0, stream>>>(P, rbV, rbC, permInt);

    scatter_coords<<<dim3((NB * NG + 255) / 256), 256, 0, stream>>>(coords, permInt, outCoords, outPerm);
    scatter_feats<<<dim3((NB * NG * 96) / 256), 256, 0, stream>>>(feats, permInt, outFeats);
}

// Round 8
// 767.203 us; speedup vs baseline: 1.7389x; 1.2746x over previous
//
#include <hip/hip_runtime.h>
#include <math.h>

#define NB 32
#define NG 512
#define NC 384
#define NH 768

// ---------------- GEMM: C = op(A @ Bw + bias). 128x128 tile, 256 threads,
// 8x8 per thread. K-accumulation order: k0 += 16, kk ascending.
// mode 0: relu, mode 1: /0.1 (scores/TAU)
__global__ __launch_bounds__(256, 2) void gemm_bias_128(
    const float* __restrict__ A, const float* __restrict__ Bw,
    const float* __restrict__ bias, float* __restrict__ Co,
    int M, int N, int K, int mode)
{
    __shared__ float sA[16][128];
    __shared__ float sB[16][128];
    int ntiles = N >> 7;
    int bm = (blockIdx.x / ntiles) << 7;
    int bn = (blockIdx.x % ntiles) << 7;
    int t = threadIdx.x;
    int tx = t & 15, ty = t >> 4;
    int tr = t >> 2, tc = t & 3;
    const float* Aptr0 = A + (size_t)(bm + tr) * K + 4 * tc;
    const float* Aptr1 = A + (size_t)(bm + 64 + tr) * K + 4 * tc;
    int kb = t >> 4, nc = t & 15;
    const float* BptrL = Bw + (size_t)kb * N + bn + 4 * nc;
    const float* BptrH = Bw + (size_t)kb * N + bn + 64 + 4 * nc;

    float acc[8][8];
#pragma unroll
    for (int i = 0; i < 8; i++)
#pragma unroll
        for (int j = 0; j < 8; j++) acc[i][j] = 0.f;

    for (int k0 = 0; k0 < K; k0 += 16) {
        float4 a0 = *(const float4*)(Aptr0 + k0);
        float4 a1 = *(const float4*)(Aptr1 + k0);
        float4 b0 = *(const float4*)(BptrL + (size_t)k0 * N);
        float4 b1 = *(const float4*)(BptrH + (size_t)k0 * N);
        __syncthreads();
        sA[4 * tc + 0][tr] = a0.x;
        sA[4 * tc + 1][tr] = a0.y;
        sA[4 * tc + 2][tr] = a0.z;
        sA[4 * tc + 3][tr] = a0.w;
        sA[4 * tc + 0][64 + tr] = a1.x;
        sA[4 * tc + 1][64 + tr] = a1.y;
        sA[4 * tc + 2][64 + tr] = a1.z;
        sA[4 * tc + 3][64 + tr] = a1.w;
        *(float4*)&sB[kb][4 * nc] = b0;
        *(float4*)&sB[kb][64 + 4 * nc] = b1;
        __syncthreads();
#pragma unroll
        for (int kk = 0; kk < 16; kk++) {
            float4 aL = *(const float4*)&sA[kk][4 * ty];
            float4 aH = *(const float4*)&sA[kk][64 + 4 * ty];
            float4 bL = *(const float4*)&sB[kk][4 * tx];
            float4 bH = *(const float4*)&sB[kk][64 + 4 * tx];
            float av[8] = { aL.x, aL.y, aL.z, aL.w, aH.x, aH.y, aH.z, aH.w };
            float bv[8] = { bL.x, bL.y, bL.z, bL.w, bH.x, bH.y, bH.z, bH.w };
#pragma unroll
            for (int i = 0; i < 8; i++)
#pragma unroll
                for (int j = 0; j < 8; j++) acc[i][j] += av[i] * bv[j];
        }
    }

    float4 blo = *(const float4*)(bias + bn + 4 * tx);
    float4 bhi = *(const float4*)(bias + bn + 64 + 4 * tx);
    float bb[8] = { blo.x, blo.y, blo.z, blo.w, bhi.x, bhi.y, bhi.z, bhi.w };
#pragma unroll
    for (int i = 0; i < 8; i++) {
        int row = bm + ((i < 4) ? (4 * ty + i) : (64 + 4 * ty + i - 4));
        float vals[8];
#pragma unroll
        for (int j = 0; j < 8; j++) {
            float val = acc[i][j] + bb[j];
            vals[j] = (mode == 0) ? fmaxf(val, 0.f) : val / 0.1f;
        }
        float4 oL; oL.x = vals[0]; oL.y = vals[1]; oL.z = vals[2]; oL.w = vals[3];
        float4 oH; oH.x = vals[4]; oH.y = vals[5]; oH.z = vals[6]; oH.w = vals[7];
        *(float4*)(Co + (size_t)row * N + bn + 4 * tx) = oL;
        *(float4*)(Co + (size_t)row * N + bn + 64 + 4 * tx) = oH;
    }
}

// ---------------- Sinkhorn: u_i = -LSE_j(A0_ij + v_j)   (one wave per row)
__global__ __launch_bounds__(256) void row_lse(
    const float* __restrict__ A0, const float* __restrict__ vv,
    float* __restrict__ uu)
{
    int wid = blockIdx.x * 4 + (threadIdx.x >> 6);
    int lane = threadIdx.x & 63;
    int b = wid >> 9;
    const float* row = A0 + (size_t)wid * NG;
    const float* vb = vv + (b << 9);
    float x[8];
    float m = -INFINITY;
#pragma unroll
    for (int e = 0; e < 8; e++) {
        int j = (e << 6) + lane;
        x[e] = row[j] + vb[j];
        m = fmaxf(m, x[e]);
    }
#pragma unroll
    for (int off = 1; off < 64; off <<= 1) m = fmaxf(m, __shfl_xor(m, off));
    float s = 0.f;
#pragma unroll
    for (int e = 0; e < 8; e++) s += expf(x[e] - m);
#pragma unroll
    for (int off = 1; off < 64; off <<= 1) s += __shfl_xor(s, off);
    if (lane == 0) uu[wid] = -(m + logf(s));
}

// ---------------- Sinkhorn col step stage A: partial online LSE over 64-row chunks
__global__ __launch_bounds__(256) void col_partial(
    const float* __restrict__ A0, const float* __restrict__ uu,
    float* __restrict__ pm, float* __restrict__ ps)
{
    int blk = blockIdx.x;
    int b = blk >> 4;
    int cc = blk & 1;
    int rc = (blk >> 1) & 7;
    int j = (cc << 8) + threadIdx.x;
    const float* base = A0 + ((size_t)(b << 9) + (rc << 6)) * NG + j;
    const float* ub = uu + (b << 9) + (rc << 6);
    float m = -INFINITY, s = 0.f;
    for (int i = 0; i < 64; i++) {
        float x = base[(size_t)i * NG] + ub[i];
        if (x > m) { s = s * expf(m - x) + 1.f; m = x; }
        else s += expf(x - m);
    }
    int o = ((b << 3) + rc) * NG + j;
    pm[o] = m; ps[o] = s;
}

// ---------------- Sinkhorn col step stage B: combine 8 partials -> v_j
__global__ __launch_bounds__(256) void col_combine(
    const float* __restrict__ pm, const float* __restrict__ ps,
    float* __restrict__ vv)
{
    int tid = blockIdx.x * 256 + threadIdx.x;
    int b = tid >> 9, j = tid & 511;
    float M = -INFINITY;
#pragma unroll
    for (int rc = 0; rc < 8; rc++) M = fmaxf(M, pm[((b << 3) + rc) * NG + j]);
    float S = 0.f;
#pragma unroll
    for (int rc = 0; rc < 8; rc++) {
        int o = ((b << 3) + rc) * NG + j;
        S += ps[o] * expf(pm[o] - M);
    }
    vv[tid] = -(M + logf(S));
}

// ======== DPP max reduce to lane 63 (pure VALU) ========
#define DPP6_MAXF(x)                                                              \
    { int _t;                                                                     \
      _t = __builtin_amdgcn_update_dpp(__float_as_int(x), __float_as_int(x),      \
               0x111, 0xf, 0xf, false); x = fmaxf(x, __int_as_float(_t));         \
      _t = __builtin_amdgcn_update_dpp(__float_as_int(x), __float_as_int(x),      \
               0x112, 0xf, 0xf, false); x = fmaxf(x, __int_as_float(_t));         \
      _t = __builtin_amdgcn_update_dpp(__float_as_int(x), __float_as_int(x),      \
               0x114, 0xf, 0xf, false); x = fmaxf(x, __int_as_float(_t));         \
      _t = __builtin_amdgcn_update_dpp(__float_as_int(x), __float_as_int(x),      \
               0x118, 0xf, 0xf, false); x = fmaxf(x, __int_as_float(_t));         \
      _t = __builtin_amdgcn_update_dpp(__float_as_int(x), __float_as_int(x),      \
               0x142, 0xa, 0xf, false); x = fmaxf(x, __int_as_float(_t));         \
      _t = __builtin_amdgcn_update_dpp(__float_as_int(x), __float_as_int(x),      \
               0x143, 0xc, 0xf, false); x = fmaxf(x, __int_as_float(_t)); }

// wave-cooperative masked row argmax over cols 8l..8l+7 per lane.
// free8 bit k = col 8l+k free. Returns (val, flat=(rr<<9)|col) of the
// (val desc, col asc) best. Requires at least one free col.
__device__ __forceinline__ void masked_row_argmax(
    const float* __restrict__ rowp, int l, unsigned int free8, int rr,
    float& outV, int& outF)
{
    float4 x0 = *(const float4*)(rowp + 8 * l);
    float4 x1 = *(const float4*)(rowp + 8 * l + 4);
    float q0 = (free8 & 1u)   ? x0.x : -1.0f;
    float q1 = (free8 & 2u)   ? x0.y : -1.0f;
    float q2 = (free8 & 4u)   ? x0.z : -1.0f;
    float q3 = (free8 & 8u)   ? x0.w : -1.0f;
    float q4 = (free8 & 16u)  ? x1.x : -1.0f;
    float q5 = (free8 & 32u)  ? x1.y : -1.0f;
    float q6 = (free8 & 64u)  ? x1.z : -1.0f;
    float q7 = (free8 & 128u) ? x1.w : -1.0f;
    float lm = fmaxf(fmaxf(fmaxf(q0, q1), fmaxf(q2, q3)),
                     fmaxf(fmaxf(q4, q5), fmaxf(q6, q7)));
    int sb = (rr << 9) + 8 * l;
    int lf = 0x7FFFFFFF;
    lf = (q7 == lm) ? sb + 7 : lf;
    lf = (q6 == lm) ? sb + 6 : lf;
    lf = (q5 == lm) ? sb + 5 : lf;
    lf = (q4 == lm) ? sb + 4 : lf;
    lf = (q3 == lm) ? sb + 3 : lf;
    lf = (q2 == lm) ? sb + 2 : lf;
    lf = (q1 == lm) ? sb + 1 : lf;
    lf = (q0 == lm) ? sb + 0 : lf;
    float gg = lm;
    DPP6_MAXF(gg)
    int ggi = __builtin_amdgcn_readlane(__float_as_int(gg), 63);
    float g1 = __int_as_float(ggi);
    unsigned long long tb = __ballot(lm == g1);
    int tl = __ffsll(tb) - 1;
    outV = g1;
    outF = __builtin_amdgcn_readlane(lf, tl);
}

// ---------------- P = exp((A0+u)+v) + per-row argmax + state init.
// One wave per row. Also: block 0 inits free masks/remaining; every wave
// writes the col-cache dirty sentinel.
__global__ __launch_bounds__(256) void p_rowmax(
    const float* __restrict__ A0, const float* __restrict__ uu,
    const float* __restrict__ vv, float* __restrict__ P,
    int* __restrict__ rbCr, int* __restrict__ rbCc,
    unsigned long long* __restrict__ freeRow,
    unsigned long long* __restrict__ freeCol,
    int* __restrict__ remaining)
{
    if (blockIdx.x == 0) {
        int t = threadIdx.x;          // 256 threads = 32 batches * 8 words
        freeRow[t] = ~0ULL;
        freeCol[t] = ~0ULL;
        if (t < NB) remaining[t] = NG;
    }
    int wrow = blockIdx.x * 4 + (threadIdx.x >> 6);
    int l = threadIdx.x & 63;
    int b = wrow >> 9;
    float ur = uu[wrow];
    const float* vb = vv + (b << 9);
    size_t ro = (size_t)wrow << 9;
    float4 a0 = *(const float4*)(A0 + ro + 8 * l);
    float4 a1 = *(const float4*)(A0 + ro + 8 * l + 4);
    float4 v0 = *(const float4*)(vb + 8 * l);
    float4 v1 = *(const float4*)(vb + 8 * l + 4);
    float p0 = expf(a0.x + ur + v0.x);
    float p1 = expf(a0.y + ur + v0.y);
    float p2 = expf(a0.z + ur + v0.z);
    float p3 = expf(a0.w + ur + v0.w);
    float p4 = expf(a1.x + ur + v1.x);
    float p5 = expf(a1.y + ur + v1.y);
    float p6 = expf(a1.z + ur + v1.z);
    float p7 = expf(a1.w + ur + v1.w);
    float4 o0; o0.x = p0; o0.y = p1; o0.z = p2; o0.w = p3;
    float4 o1; o1.x = p4; o1.y = p5; o1.z = p6; o1.w = p7;
    *(float4*)(P + ro + 8 * l) = o0;
    *(float4*)(P + ro + 8 * l + 4) = o1;
    float mv = fmaxf(fmaxf(fmaxf(p0, p1), fmaxf(p2, p3)),
                     fmaxf(fmaxf(p4, p5), fmaxf(p6, p7)));
    int cb = 8 * l;
    int f = 0x7FFFFFFF;
    f = (p7 == mv) ? cb + 7 : f;
    f = (p6 == mv) ? cb + 6 : f;
    f = (p5 == mv) ? cb + 5 : f;
    f = (p4 == mv) ? cb + 4 : f;
    f = (p3 == mv) ? cb + 3 : f;
    f = (p2 == mv) ? cb + 2 : f;
    f = (p1 == mv) ? cb + 1 : f;
    f = (p0 == mv) ? cb + 0 : f;
    float g = mv;
    DPP6_MAXF(g)
    int gi = __builtin_amdgcn_readlane(__float_as_int(g), 63);
    float gm = __int_as_float(gi);
    unsigned long long tb = __ballot(mv == gm);
    int tl = __ffsll(tb) - 1;
    int bestc = __builtin_amdgcn_readlane(f, tl);
    if (l == 0) { rbCr[wrow] = bestc; rbCc[wrow] = -1; }
}

// ---------------- One parallel mutual-max round (exact greedy equivalence).
// Take every entry that is key-min ((val desc, flat asc)) of BOTH its row and
// its col among the free submatrix. Row/col argmax caches persist across
// rounds; a cache is valid iff its partner is still free.
__global__ __launch_bounds__(512) void mutual_round(
    const float* __restrict__ P, int* __restrict__ rbCr, int* __restrict__ rbCc,
    unsigned long long* __restrict__ freeRow,
    unsigned long long* __restrict__ freeCol,
    int* __restrict__ remaining, int* __restrict__ permInt)
{
    int b = blockIdx.x;
    if (remaining[b] == 0) return;
    int t = threadIdx.x;
    int l = t & 63;
    int w = t >> 6;
    const float* Pb = P + (size_t)b * NG * NG;

    __shared__ unsigned int fr[16], fc[16];
    __shared__ int sRC[NG];
    __shared__ int sCC[NG];
    __shared__ int freeList[NG];
    __shared__ int dirtyRows[NG];
    __shared__ int nFree, nDirtyRow, takeCnt;
    __shared__ int wCnt[8], wOff[8];

    if (t < 8) {
        unsigned long long x = freeRow[b * 8 + t];
        fr[2 * t] = (unsigned)x; fr[2 * t + 1] = (unsigned)(x >> 32);
    } else if (t < 16) {
        int i = t - 8;
        unsigned long long x = freeCol[b * 8 + i];
        fc[2 * i] = (unsigned)x; fc[2 * i + 1] = (unsigned)(x >> 32);
    }
    sRC[t] = rbCr[(b << 9) + t];
    sCC[t] = rbCc[(b << 9) + t];
    if (t == 0) { nDirtyRow = 0; takeCnt = 0; }
    __syncthreads();

    // free-row list (ascending) + dirty-row list
    bool isFree = (fr[t >> 5] >> (t & 31)) & 1u;
    unsigned long long bm = __ballot(isFree);
    if (l == 0) wCnt[w] = __popcll(bm);
    if (isFree) {
        int c = sRC[t];
        if (!((fc[c >> 5] >> (c & 31)) & 1u)) {
            int d = atomicAdd(&nDirtyRow, 1);
            dirtyRows[d] = t;
        }
    }
    __syncthreads();
    if (t == 0) {
        int s = 0;
#pragma unroll
        for (int i = 0; i < 8; i++) { wOff[i] = s; s += wCnt[i]; }
        nFree = s;
    }
    __syncthreads();
    if (isFree) {
        int rank = __popcll(bm & ((1ULL << l) - 1ULL));
        freeList[wOff[w] + rank] = t;
    }
    __syncthreads();

    // phase 1: rescan dirty rows (wave-cooperative)
    int nd = nDirtyRow;
    for (int d = w; d < nd; d += 8) {
        int r = dirtyRows[d];
        unsigned int free8 = (fc[l >> 2] >> ((l & 3) * 8)) & 0xFFu;
        float nv; int nf;
        masked_row_argmax(Pb + ((size_t)r << 9), l, free8, r, nv, nf);
        if (l == 0) {
            int c = nf & 511;
            sRC[r] = c;
            rbCr[(b << 9) + r] = c;
        }
    }
    __syncthreads();

    // phase 2: rescan dirty cols (thread per col, loop free rows ascending)
    bool colFree = (fc[t >> 5] >> (t & 31)) & 1u;
    int cachedR = sCC[t];
    bool colDirty = colFree &&
        (cachedR < 0 || !((fr[cachedR >> 5] >> (cachedR & 31)) & 1u));
    if (colDirty) {
        float best = -1.f; int bestr = 0x7FFFFFFF;
        int nf2 = nFree;
        int i = 0;
        for (; i + 4 <= nf2; i += 4) {
            int r0 = freeList[i], r1 = freeList[i + 1];
            int r2 = freeList[i + 2], r3 = freeList[i + 3];
            float v0 = Pb[((size_t)r0 << 9) + t];
            float v1 = Pb[((size_t)r1 << 9) + t];
            float v2 = Pb[((size_t)r2 << 9) + t];
            float v3 = Pb[((size_t)r3 << 9) + t];
            if (v0 > best) { best = v0; bestr = r0; }
            if (v1 > best) { best = v1; bestr = r1; }
            if (v2 > best) { best = v2; bestr = r2; }
            if (v3 > best) { best = v3; bestr = r3; }
        }
        for (; i < nf2; ++i) {
            int ri = freeList[i];
            float vv2 = Pb[((size_t)ri << 9) + t];
            if (vv2 > best) { best = vv2; bestr = ri; }
        }
        sCC[t] = bestr;
        rbCc[(b << 9) + t] = bestr;
    }
    __syncthreads();

    // phase 3: decide (mutual agreement). Only thread t clears col bit t;
    // fr bits are not read in this phase -> no read/write hazard.
    if (colFree) {
        int r = sCC[t];
        if (r >= 0 && r < NG && sRC[r] == t) {
            permInt[(b << 9) + r] = t;
            atomicAnd(&fr[r >> 5], ~(1u << (r & 31)));
            atomicAnd(&fc[t >> 5], ~(1u << (t & 31)));
            atomicAdd(&takeCnt, 1);
        }
    }
    __syncthreads();
    if (t < 8) {
        freeRow[b * 8 + t] =
            ((unsigned long long)fr[2 * t + 1] << 32) | fr[2 * t];
    } else if (t < 16) {
        int i = t - 8;
        freeCol[b * 8 + i] =
            ((unsigned long long)fc[2 * i + 1] << 32) | fc[2 * i];
    }
    if (t == 0) remaining[b] = remaining[b] - takeCnt;
}

// ---------------- Exact sequential cleanup for any rows the fixed number of
// parallel rounds didn't assign (usually zero). greedy6 machinery with early
// exit; writes perm per take.
__global__ __launch_bounds__(64) void greedy_cleanup(
    const float* __restrict__ P,
    const unsigned long long* __restrict__ freeRow,
    const unsigned long long* __restrict__ freeCol,
    const int* __restrict__ remaining, int* __restrict__ permInt)
{
    int b = blockIdx.x;
    if (remaining[b] == 0) return;
    int l = threadIdx.x;
    const float* Pb = P + (size_t)b * NG * NG;

    unsigned long long wR = freeRow[b * 8 + (l >> 3)];
    unsigned int myRows = (unsigned int)((wR >> ((l & 7) * 8)) & 0xFF);
    unsigned long long wC = freeCol[b * 8 + (l >> 3)];
    unsigned int free8 = (unsigned int)((wC >> ((l & 7) * 8)) & 0xFF);

    float rv[8]; int rf[8];
#pragma unroll
    for (int k = 0; k < 8; k++) { rv[k] = -1.f; rf[k] = 0x7FFFFFFF; }

    // initial rescans for my free rows
    int dmk = (int)myRows;
    unsigned long long act = __ballot(dmk != 0);
    while (act) {
        int src = __ffsll(act) - 1;
        int kk = __ffs(__builtin_amdgcn_readlane(dmk, src)) - 1;
        if (l == src) dmk &= ~(1 << kk);
        int rr = (src << 3) + kk;
        float nv; int nf;
        masked_row_argmax(Pb + ((size_t)rr << 9), l, free8, rr, nv, nf);
        bool upd = (l == src);
        rv[0] = (upd && kk == 0) ? nv : rv[0]; rf[0] = (upd && kk == 0) ? nf : rf[0];
        rv[1] = (upd && kk == 1) ? nv : rv[1]; rf[1] = (upd && kk == 1) ? nf : rf[1];
        rv[2] = (upd && kk == 2) ? nv : rv[2]; rf[2] = (upd && kk == 2) ? nf : rf[2];
        rv[3] = (upd && kk == 3) ? nv : rv[3]; rf[3] = (upd && kk == 3) ? nf : rf[3];
        rv[4] = (upd && kk == 4) ? nv : rv[4]; rf[4] = (upd && kk == 4) ? nf : rf[4];
        rv[5] = (upd && kk == 5) ? nv : rv[5]; rf[5] = (upd && kk == 5) ? nf : rf[5];
        rv[6] = (upd && kk == 6) ? nv : rv[6]; rf[6] = (upd && kk == 6) ? nf : rf[6];
        rv[7] = (upd && kk == 7) ? nv : rv[7]; rf[7] = (upd && kk == 7) ? nf : rf[7];
        act = __ballot(dmk != 0);
    }

    for (int step = 0; step < NG; ++step) {
        float mv = fmaxf(fmaxf(fmaxf(rv[0], rv[1]), fmaxf(rv[2], rv[3])),
                         fmaxf(fmaxf(rv[4], rv[5]), fmaxf(rv[6], rv[7])));
        int f = 0x7FFFFFFF;
        f = (rv[7] == mv) ? rf[7] : f;
        f = (rv[6] == mv) ? rf[6] : f;
        f = (rv[5] == mv) ? rf[5] : f;
        f = (rv[4] == mv) ? rf[4] : f;
        f = (rv[3] == mv) ? rf[3] : f;
        f = (rv[2] == mv) ? rf[2] : f;
        f = (rv[1] == mv) ? rf[1] : f;
        f = (rv[0] == mv) ? rf[0] : f;
        float g = mv;
        DPP6_MAXF(g)
        int gi = __builtin_amdgcn_readlane(__float_as_int(g), 63);
        float gm = __int_as_float(gi);
        if (gm < 0.f) break;     // all assigned
        unsigned long long tb = __ballot(mv == gm);
        int tl = __ffsll(tb) - 1;
        int bestf = __builtin_amdgcn_readlane(f, tl);
        int r = bestf >> 9, c = bestf & 511;
        if (l == 0) permInt[(b << 9) + r] = c;
        if (l == (c >> 3)) free8 &= ~(1u << (c & 7));
        int rl = r - (l << 3);
        int dm2 = 0;
#pragma unroll
        for (int k = 0; k < 8; k++) {
            bool alive = rv[k] >= 0.f;
            bool cm = ((rf[k] ^ c) & 511) == 0;
            bool taken = (rl == k);
            if (taken) rv[k] = -1.f;
            dm2 |= (alive && cm && !taken) ? (1 << k) : 0;
        }
        unsigned long long act2 = __ballot(dm2 != 0);
        while (act2) {
            int src = __ffsll(act2) - 1;
            int kk = __ffs(__builtin_amdgcn_readlane(dm2, src)) - 1;
            if (l == src) dm2 &= ~(1 << kk);
            int rr = (src << 3) + kk;
            float nv; int nf;
            masked_row_argmax(Pb + ((size_t)rr << 9), l, free8, rr, nv, nf);
            bool upd = (l == src);
            rv[0] = (upd && kk == 0) ? nv : rv[0]; rf[0] = (upd && kk == 0) ? nf : rf[0];
            rv[1] = (upd && kk == 1) ? nv : rv[1]; rf[1] = (upd && kk == 1) ? nf : rf[1];
            rv[2] = (upd && kk == 2) ? nv : rv[2]; rf[2] = (upd && kk == 2) ? nf : rf[2];
            rv[3] = (upd && kk == 3) ? nv : rv[3]; rf[3] = (upd && kk == 3) ? nf : rf[3];
            rv[4] = (upd && kk == 4) ? nv : rv[4]; rf[4] = (upd && kk == 4) ? nf : rf[4];
            rv[5] = (upd && kk == 5) ? nv : rv[5]; rf[5] = (upd && kk == 5) ? nf : rf[5];
            rv[6] = (upd && kk == 6) ? nv : rv[6]; rf[6] = (upd && kk == 6) ? nf : rf[6];
            rv[7] = (upd && kk == 7) ? nv : rv[7]; rf[7] = (upd && kk == 7) ? nf : rf[7];
            act2 = __ballot(dm2 != 0);
        }
    }
}

// ---------------- apply permutation: out[b][perm[r]] = in[b][r]
__global__ void scatter_coords(const float* __restrict__ src,
    const int* __restrict__ perm, float* __restrict__ dst,
    float* __restrict__ permF)
{
    int tid = blockIdx.x * 256 + threadIdx.x;
    if (tid >= NB * NG) return;
    int b = tid >> 9;
    int p = perm[tid];
    permF[tid] = (float)p;
    size_t so = (size_t)tid * 3;
    size_t dd = ((size_t)(b << 9) + p) * 3;
    dst[dd] = src[so]; dst[dd + 1] = src[so + 1]; dst[dd + 2] = src[so + 2];
}

__global__ void scatter_feats(const float* __restrict__ src,
    const int* __restrict__ perm, float* __restrict__ dst)
{
    int tid = blockIdx.x * 256 + threadIdx.x;
    int rc = tid / 96;
    int q = tid - rc * 96;
    int b = rc >> 9;
    int p = perm[rc];
    const float4* s4 = (const float4*)(src + (size_t)rc * NC);
    float4* d4 = (float4*)(dst + ((size_t)(b << 9) + p) * NC);
    d4[q] = s4[q];
}

extern "C" void kernel_launch(void* const* d_in, const int* in_sizes, int n_in,
                              void* d_out, int out_size, void* d_ws, size_t ws_size,
                              hipStream_t stream)
{
    const float* coords = (const float*)d_in[0];
    const float* feats  = (const float*)d_in[1];
    const float* W1 = (const float*)d_in[2];
    const float* b1 = (const float*)d_in[3];
    const float* W2 = (const float*)d_in[4];
    const float* b2 = (const float*)d_in[5];

    float* out = (float*)d_out;
    float* outCoords = out;
    float* outFeats  = out + (size_t)NB * NG * 3;
    float* outPerm   = out + (size_t)NB * NG * 3 + (size_t)NB * NG * NC;

    float* ws = (float*)d_ws;
    float* h   = ws;                                  // 16384*768 (reused as P)
    float* A0  = h + (size_t)NB * NG * NH;            // 16384*512
    float* u   = A0 + (size_t)NB * NG * NG;           // 16384
    float* v   = u + NB * NG;                         // 16384
    float* pm  = v + NB * NG;                         // 32*8*512
    float* ps  = pm + NB * 8 * NG;                    // 32*8*512
    int* rbCr  = (int*)(ps + NB * 8 * NG);            // 16384
    int* rbCc  = rbCr + NB * NG;                      // 16384
    unsigned long long* freeRow = (unsigned long long*)(rbCc + NB * NG); // 256
    unsigned long long* freeCol = freeRow + NB * 8;   // 256
    int* remaining = (int*)(freeCol + NB * 8);        // 32
    int* permInt   = remaining + 32;                  // 16384

    const int M = NB * NG;  // 16384

    // h = relu(feats @ W1 + b1)
    gemm_bias_128<<<dim3((M / 128) * (NH / 128)), 256, 0, stream>>>(
        feats, W1, b1, h, M, NH, NC, 0);
    // A0 = (h @ W2 + b2) / TAU
    gemm_bias_128<<<dim3((M / 128) * (NG / 128)), 256, 0, stream>>>(
        h, W2, b2, A0, M, NG, NH, 1);

    hipMemsetAsync(v, 0, (size_t)NB * NG * sizeof(float), stream);

    for (int it = 0; it < 10; ++it) {
        row_lse<<<dim3(M / 4), 256, 0, stream>>>(A0, v, u);
        col_partial<<<dim3(NB * 16), 256, 0, stream>>>(A0, u, pm, ps);
        col_combine<<<dim3(M / 256), 256, 0, stream>>>(pm, ps, v);
    }

    // P + row caches + state init
    float* P = h;
    p_rowmax<<<dim3(M / 4), 256, 0, stream>>>(A0, u, v, P, rbCr, rbCc,
                                              freeRow, freeCol, remaining);

    // parallel exact-greedy rounds (early-exit when a batch completes)
    for (int r = 0; r < 10; ++r)
        mutual_round<<<dim3(NB), 512, 0, stream>>>(P, rbCr, rbCc, freeRow,
                                                   freeCol, remaining, permInt);

    // exact sequential cleanup for anything left
    greedy_cleanup<<<dim3(NB), 64, 0, stream>>>(P, freeRow, freeCol,
                                                remaining, permInt);

    scatter_coords<<<dim3((NB * NG + 255) / 256), 256, 0, stream>>>(coords, permInt, outCoords, outPerm);
    scatter_feats<<<dim3((NB * NG * 96) / 256), 256, 0, stream>>>(feats, permInt, outFeats);
}

// Round 9
// 553.413 us; speedup vs baseline: 2.4107x; 1.3863x over previous
//
#include <hip/hip_runtime.h>
#include <math.h>

#define NB 32
#define NG 512
#define NC 384
#define NH 768

typedef float __attribute__((ext_vector_type(2))) f32x2;

// ---------------- GEMM: C = op(A @ Bw + bias). 128x128 tile, 256 threads,
// 8x8 per thread via f32x2 packed FMA (per-lane fma -> bit-identical to
// scalar). LDS rows padded to 132 floats: staging-write banks become <=2-way.
// K order: k0 += 16, kk ascending. mode 0: relu, mode 1: /0.1 (scores/TAU)
__global__ __launch_bounds__(256, 2) void gemm_bias_128(
    const float* __restrict__ A, const float* __restrict__ Bw,
    const float* __restrict__ bias, float* __restrict__ Co,
    int M, int N, int K, int mode)
{
    __shared__ float sA[16][132];
    __shared__ float sB[16][132];
    int ntiles = N >> 7;
    int bm = (blockIdx.x / ntiles) << 7;
    int bn = (blockIdx.x % ntiles) << 7;
    int t = threadIdx.x;
    int tx = t & 15, ty = t >> 4;
    int tr = t >> 2, tc = t & 3;
    const float* Aptr0 = A + (size_t)(bm + tr) * K + 4 * tc;
    const float* Aptr1 = A + (size_t)(bm + 64 + tr) * K + 4 * tc;
    int kb = t >> 4, nc = t & 15;
    const float* BptrL = Bw + (size_t)kb * N + bn + 4 * nc;
    const float* BptrH = Bw + (size_t)kb * N + bn + 64 + 4 * nc;

    f32x2 acc2[8][4];
#pragma unroll
    for (int i = 0; i < 8; i++)
#pragma unroll
        for (int j = 0; j < 4; j++) acc2[i][j] = (f32x2)(0.f);

    for (int k0 = 0; k0 < K; k0 += 16) {
        float4 a0 = *(const float4*)(Aptr0 + k0);
        float4 a1 = *(const float4*)(Aptr1 + k0);
        float4 b0 = *(const float4*)(BptrL + (size_t)k0 * N);
        float4 b1 = *(const float4*)(BptrH + (size_t)k0 * N);
        __syncthreads();
        sA[4 * tc + 0][tr] = a0.x;
        sA[4 * tc + 1][tr] = a0.y;
        sA[4 * tc + 2][tr] = a0.z;
        sA[4 * tc + 3][tr] = a0.w;
        sA[4 * tc + 0][64 + tr] = a1.x;
        sA[4 * tc + 1][64 + tr] = a1.y;
        sA[4 * tc + 2][64 + tr] = a1.z;
        sA[4 * tc + 3][64 + tr] = a1.w;
        *(float4*)&sB[kb][4 * nc] = b0;
        *(float4*)&sB[kb][64 + 4 * nc] = b1;
        __syncthreads();
#pragma unroll
        for (int kk = 0; kk < 16; kk++) {
            float4 aL = *(const float4*)&sA[kk][4 * ty];
            float4 aH = *(const float4*)&sA[kk][64 + 4 * ty];
            float4 bL = *(const float4*)&sB[kk][4 * tx];
            float4 bH = *(const float4*)&sB[kk][64 + 4 * tx];
            float av[8] = { aL.x, aL.y, aL.z, aL.w, aH.x, aH.y, aH.z, aH.w };
            f32x2 bb[4];
            bb[0].x = bL.x; bb[0].y = bL.y;
            bb[1].x = bL.z; bb[1].y = bL.w;
            bb[2].x = bH.x; bb[2].y = bH.y;
            bb[3].x = bH.z; bb[3].y = bH.w;
#pragma unroll
            for (int i = 0; i < 8; i++) {
                f32x2 aa; aa.x = av[i]; aa.y = av[i];
#pragma unroll
                for (int j = 0; j < 4; j++)
                    acc2[i][j] = __builtin_elementwise_fma(aa, bb[j], acc2[i][j]);
            }
        }
    }

    float4 blo = *(const float4*)(bias + bn + 4 * tx);
    float4 bhi = *(const float4*)(bias + bn + 64 + 4 * tx);
    float bb8[8] = { blo.x, blo.y, blo.z, blo.w, bhi.x, bhi.y, bhi.z, bhi.w };
#pragma unroll
    for (int i = 0; i < 8; i++) {
        int row = bm + ((i < 4) ? (4 * ty + i) : (64 + 4 * ty + i - 4));
        float vals[8];
        vals[0] = acc2[i][0].x + bb8[0];
        vals[1] = acc2[i][0].y + bb8[1];
        vals[2] = acc2[i][1].x + bb8[2];
        vals[3] = acc2[i][1].y + bb8[3];
        vals[4] = acc2[i][2].x + bb8[4];
        vals[5] = acc2[i][2].y + bb8[5];
        vals[6] = acc2[i][3].x + bb8[6];
        vals[7] = acc2[i][3].y + bb8[7];
#pragma unroll
        for (int j = 0; j < 8; j++)
            vals[j] = (mode == 0) ? fmaxf(vals[j], 0.f) : vals[j] / 0.1f;
        float4 oL; oL.x = vals[0]; oL.y = vals[1]; oL.z = vals[2]; oL.w = vals[3];
        float4 oH; oH.x = vals[4]; oH.y = vals[5]; oH.z = vals[6]; oH.w = vals[7];
        *(float4*)(Co + (size_t)row * N + bn + 4 * tx) = oL;
        *(float4*)(Co + (size_t)row * N + bn + 64 + 4 * tx) = oH;
    }
}

// ======== DPP reduce networks to lane 63 (pure VALU) ========
#define DPP6_MAXF(x)                                                              \
    { int _t;                                                                     \
      _t = __builtin_amdgcn_update_dpp(__float_as_int(x), __float_as_int(x),      \
               0x111, 0xf, 0xf, false); x = fmaxf(x, __int_as_float(_t));         \
      _t = __builtin_amdgcn_update_dpp(__float_as_int(x), __float_as_int(x),      \
               0x112, 0xf, 0xf, false); x = fmaxf(x, __int_as_float(_t));         \
      _t = __builtin_amdgcn_update_dpp(__float_as_int(x), __float_as_int(x),      \
               0x114, 0xf, 0xf, false); x = fmaxf(x, __int_as_float(_t));         \
      _t = __builtin_amdgcn_update_dpp(__float_as_int(x), __float_as_int(x),      \
               0x118, 0xf, 0xf, false); x = fmaxf(x, __int_as_float(_t));         \
      _t = __builtin_amdgcn_update_dpp(__float_as_int(x), __float_as_int(x),      \
               0x142, 0xa, 0xf, false); x = fmaxf(x, __int_as_float(_t));         \
      _t = __builtin_amdgcn_update_dpp(__float_as_int(x), __float_as_int(x),      \
               0x143, 0xc, 0xf, false); x = fmaxf(x, __int_as_float(_t)); }

#define DPP6_ADDF(x)                                                              \
    { int _t;                                                                     \
      _t = __builtin_amdgcn_update_dpp(__float_as_int(x), __float_as_int(x),      \
               0x111, 0xf, 0xf, false); x = x + __int_as_float(_t);               \
      _t = __builtin_amdgcn_update_dpp(__float_as_int(x), __float_as_int(x),      \
               0x112, 0xf, 0xf, false); x = x + __int_as_float(_t);               \
      _t = __builtin_amdgcn_update_dpp(__float_as_int(x), __float_as_int(x),      \
               0x114, 0xf, 0xf, false); x = x + __int_as_float(_t);               \
      _t = __builtin_amdgcn_update_dpp(__float_as_int(x), __float_as_int(x),      \
               0x118, 0xf, 0xf, false); x = x + __int_as_float(_t);               \
      _t = __builtin_amdgcn_update_dpp(__float_as_int(x), __float_as_int(x),      \
               0x142, 0xa, 0xf, false); x = x + __int_as_float(_t);               \
      _t = __builtin_amdgcn_update_dpp(__float_as_int(x), __float_as_int(x),      \
               0x143, 0xc, 0xf, false); x = x + __int_as_float(_t); }

// ---------------- Fused Sinkhorn half-iterations: one pass over A0 computes
// u = -LSE_row(A0+v) AND linear-domain column partials sum_i exp(A0+u+v)
// (reusing the row exponentials: term = e1/s <= 1, no overflow).
// Block = 64 rows of one batch (NB*8 blocks); wave w handles 16 rows; lane l
// owns cols {4l..4l+3, 256+4l..256+4l+3} across all rows.
__global__ __launch_bounds__(256) void sinkhorn_iter(
    const float* __restrict__ A0, float* __restrict__ uu,
    const float* __restrict__ vv, float* __restrict__ ps)
{
    int blk = blockIdx.x;          // NB*8
    int b = blk >> 3, rc = blk & 7;
    int t = threadIdx.x;
    int l = t & 63, w = t >> 6;
    const float* vb = vv + (b << 9);
    float4 v0 = *(const float4*)(vb + 4 * l);
    float4 v1 = *(const float4*)(vb + 256 + 4 * l);
    int row0 = (rc << 6) + (w << 4);
    const float* base = A0 + ((size_t)((b << 9) + row0) << 9);

    float cs0 = 0.f, cs1 = 0.f, cs2 = 0.f, cs3 = 0.f;
    float cs4 = 0.f, cs5 = 0.f, cs6 = 0.f, cs7 = 0.f;

    for (int rr = 0; rr < 16; ++rr) {
        const float* rowp = base + ((size_t)rr << 9);
        float4 a0 = *(const float4*)(rowp + 4 * l);
        float4 a1 = *(const float4*)(rowp + 256 + 4 * l);
        float x0 = a0.x + v0.x, x1 = a0.y + v0.y;
        float x2 = a0.z + v0.z, x3 = a0.w + v0.w;
        float x4 = a1.x + v1.x, x5 = a1.y + v1.y;
        float x6 = a1.z + v1.z, x7 = a1.w + v1.w;
        float m = fmaxf(fmaxf(fmaxf(x0, x1), fmaxf(x2, x3)),
                        fmaxf(fmaxf(x4, x5), fmaxf(x6, x7)));
        DPP6_MAXF(m)
        int mi = __builtin_amdgcn_readlane(__float_as_int(m), 63);
        m = __int_as_float(mi);
        float e0 = __expf(x0 - m), e1 = __expf(x1 - m);
        float e2 = __expf(x2 - m), e3 = __expf(x3 - m);
        float e4 = __expf(x4 - m), e5 = __expf(x5 - m);
        float e6 = __expf(x6 - m), e7 = __expf(x7 - m);
        float s = ((e0 + e1) + (e2 + e3)) + ((e4 + e5) + (e6 + e7));
        DPP6_ADDF(s)
        int si = __builtin_amdgcn_readlane(__float_as_int(s), 63);
        s = __int_as_float(si);
        float inv = 1.0f / s;
        cs0 += e0 * inv; cs1 += e1 * inv; cs2 += e2 * inv; cs3 += e3 * inv;
        cs4 += e4 * inv; cs5 += e5 * inv; cs6 += e6 * inv; cs7 += e7 * inv;
        if (l == 63) uu[(b << 9) + row0 + rr] = -(m + __logf(s));
    }

    // merge 4 waves' per-lane column partials
    __shared__ float sacc[4][512];
    float4 w0; w0.x = cs0; w0.y = cs1; w0.z = cs2; w0.w = cs3;
    float4 w1; w1.x = cs4; w1.y = cs5; w1.z = cs6; w1.w = cs7;
    *(float4*)&sacc[w][4 * l] = w0;
    *(float4*)&sacc[w][256 + 4 * l] = w1;
    __syncthreads();
    float pA = sacc[0][t] + sacc[1][t] + sacc[2][t] + sacc[3][t];
    float pB = sacc[0][256 + t] + sacc[1][256 + t] + sacc[2][256 + t] + sacc[3][256 + t];
    int o = ((b << 3) + rc) * NG;
    ps[o + t] = pA;
    ps[o + 256 + t] = pB;
}

// ---------------- combine 8 linear partials -> v' = v - log(colsum)
__global__ __launch_bounds__(256) void col_combine_lin(
    const float* __restrict__ ps, float* __restrict__ vv)
{
    int tid = blockIdx.x * 256 + threadIdx.x;  // NB*NG
    int b = tid >> 9, j = tid & 511;
    float S = 0.f;
#pragma unroll
    for (int rc = 0; rc < 8; rc++) S += ps[((b << 3) + rc) * NG + j];
    vv[tid] = vv[tid] - __logf(S);
}

// wave-cooperative masked row argmax over cols 8l..8l+7 per lane.
__device__ __forceinline__ void masked_row_argmax(
    const float* __restrict__ rowp, int l, unsigned int free8, int rr,
    float& outV, int& outF)
{
    float4 x0 = *(const float4*)(rowp + 8 * l);
    float4 x1 = *(const float4*)(rowp + 8 * l + 4);
    float q0 = (free8 & 1u)   ? x0.x : -1.0f;
    float q1 = (free8 & 2u)   ? x0.y : -1.0f;
    float q2 = (free8 & 4u)   ? x0.z : -1.0f;
    float q3 = (free8 & 8u)   ? x0.w : -1.0f;
    float q4 = (free8 & 16u)  ? x1.x : -1.0f;
    float q5 = (free8 & 32u)  ? x1.y : -1.0f;
    float q6 = (free8 & 64u)  ? x1.z : -1.0f;
    float q7 = (free8 & 128u) ? x1.w : -1.0f;
    float lm = fmaxf(fmaxf(fmaxf(q0, q1), fmaxf(q2, q3)),
                     fmaxf(fmaxf(q4, q5), fmaxf(q6, q7)));
    int sb = (rr << 9) + 8 * l;
    int lf = 0x7FFFFFFF;
    lf = (q7 == lm) ? sb + 7 : lf;
    lf = (q6 == lm) ? sb + 6 : lf;
    lf = (q5 == lm) ? sb + 5 : lf;
    lf = (q4 == lm) ? sb + 4 : lf;
    lf = (q3 == lm) ? sb + 3 : lf;
    lf = (q2 == lm) ? sb + 2 : lf;
    lf = (q1 == lm) ? sb + 1 : lf;
    lf = (q0 == lm) ? sb + 0 : lf;
    float gg = lm;
    DPP6_MAXF(gg)
    int ggi = __builtin_amdgcn_readlane(__float_as_int(gg), 63);
    float g1 = __int_as_float(ggi);
    unsigned long long tb = __ballot(lm == g1);
    int tl = __ffsll(tb) - 1;
    outV = g1;
    outF = __builtin_amdgcn_readlane(lf, tl);
}

// ---------------- P = exp((A0+u)+v) (libm expf: tail/tie behavior must match
// np) + per-row argmax + state init.
__global__ __launch_bounds__(256) void p_rowmax(
    const float* __restrict__ A0, const float* __restrict__ uu,
    const float* __restrict__ vv, float* __restrict__ P,
    int* __restrict__ rbCr, int* __restrict__ rbCc,
    unsigned long long* __restrict__ freeRow,
    unsigned long long* __restrict__ freeCol,
    int* __restrict__ remaining)
{
    if (blockIdx.x == 0) {
        int t = threadIdx.x;
        freeRow[t] = ~0ULL;
        freeCol[t] = ~0ULL;
        if (t < NB) remaining[t] = NG;
    }
    int wrow = blockIdx.x * 4 + (threadIdx.x >> 6);
    int l = threadIdx.x & 63;
    int b = wrow >> 9;
    float ur = uu[wrow];
    const float* vb = vv + (b << 9);
    size_t ro = (size_t)wrow << 9;
    float4 a0 = *(const float4*)(A0 + ro + 8 * l);
    float4 a1 = *(const float4*)(A0 + ro + 8 * l + 4);
    float4 v0 = *(const float4*)(vb + 8 * l);
    float4 v1 = *(const float4*)(vb + 8 * l + 4);
    float p0 = expf(a0.x + ur + v0.x);
    float p1 = expf(a0.y + ur + v0.y);
    float p2 = expf(a0.z + ur + v0.z);
    float p3 = expf(a0.w + ur + v0.w);
    float p4 = expf(a1.x + ur + v1.x);
    float p5 = expf(a1.y + ur + v1.y);
    float p6 = expf(a1.z + ur + v1.z);
    float p7 = expf(a1.w + ur + v1.w);
    float4 o0; o0.x = p0; o0.y = p1; o0.z = p2; o0.w = p3;
    float4 o1; o1.x = p4; o1.y = p5; o1.z = p6; o1.w = p7;
    *(float4*)(P + ro + 8 * l) = o0;
    *(float4*)(P + ro + 8 * l + 4) = o1;
    float mv = fmaxf(fmaxf(fmaxf(p0, p1), fmaxf(p2, p3)),
                     fmaxf(fmaxf(p4, p5), fmaxf(p6, p7)));
    int cb = 8 * l;
    int f = 0x7FFFFFFF;
    f = (p7 == mv) ? cb + 7 : f;
    f = (p6 == mv) ? cb + 6 : f;
    f = (p5 == mv) ? cb + 5 : f;
    f = (p4 == mv) ? cb + 4 : f;
    f = (p3 == mv) ? cb + 3 : f;
    f = (p2 == mv) ? cb + 2 : f;
    f = (p1 == mv) ? cb + 1 : f;
    f = (p0 == mv) ? cb + 0 : f;
    float g = mv;
    DPP6_MAXF(g)
    int gi = __builtin_amdgcn_readlane(__float_as_int(g), 63);
    float gm = __int_as_float(gi);
    unsigned long long tb = __ballot(mv == gm);
    int tl = __ffsll(tb) - 1;
    int bestc = __builtin_amdgcn_readlane(f, tl);
    if (l == 0) { rbCr[wrow] = bestc; rbCc[wrow] = -1; }
}

// ---------------- One parallel mutual-max round (exact greedy equivalence).
__global__ __launch_bounds__(512) void mutual_round(
    const float* __restrict__ P, int* __restrict__ rbCr, int* __restrict__ rbCc,
    unsigned long long* __restrict__ freeRow,
    unsigned long long* __restrict__ freeCol,
    int* __restrict__ remaining, int* __restrict__ permInt)
{
    int b = blockIdx.x;
    if (remaining[b] == 0) return;
    int t = threadIdx.x;
    int l = t & 63;
    int w = t >> 6;
    const float* Pb = P + (size_t)b * NG * NG;

    __shared__ unsigned int fr[16], fc[16];
    __shared__ int sRC[NG];
    __shared__ int sCC[NG];
    __shared__ int freeList[NG];
    __shared__ int dirtyRows[NG];
    __shared__ int nFree, nDirtyRow, takeCnt;
    __shared__ int wCnt[8], wOff[8];

    if (t < 8) {
        unsigned long long x = freeRow[b * 8 + t];
        fr[2 * t] = (unsigned)x; fr[2 * t + 1] = (unsigned)(x >> 32);
    } else if (t < 16) {
        int i = t - 8;
        unsigned long long x = freeCol[b * 8 + i];
        fc[2 * i] = (unsigned)x; fc[2 * i + 1] = (unsigned)(x >> 32);
    }
    sRC[t] = rbCr[(b << 9) + t];
    sCC[t] = rbCc[(b << 9) + t];
    if (t == 0) { nDirtyRow = 0; takeCnt = 0; }
    __syncthreads();

    bool isFree = (fr[t >> 5] >> (t & 31)) & 1u;
    unsigned long long bm = __ballot(isFree);
    if (l == 0) wCnt[w] = __popcll(bm);
    if (isFree) {
        int c = sRC[t];
        if (!((fc[c >> 5] >> (c & 31)) & 1u)) {
            int d = atomicAdd(&nDirtyRow, 1);
            dirtyRows[d] = t;
        }
    }
    __syncthreads();
    if (t == 0) {
        int s = 0;
#pragma unroll
        for (int i = 0; i < 8; i++) { wOff[i] = s; s += wCnt[i]; }
        nFree = s;
    }
    __syncthreads();
    if (isFree) {
        int rank = __popcll(bm & ((1ULL << l) - 1ULL));
        freeList[wOff[w] + rank] = t;
    }
    __syncthreads();

    int nd = nDirtyRow;
    for (int d = w; d < nd; d += 8) {
        int r = dirtyRows[d];
        unsigned int free8 = (fc[l >> 2] >> ((l & 3) * 8)) & 0xFFu;
        float nv; int nf;
        masked_row_argmax(Pb + ((size_t)r << 9), l, free8, r, nv, nf);
        if (l == 0) {
            int c = nf & 511;
            sRC[r] = c;
            rbCr[(b << 9) + r] = c;
        }
    }
    __syncthreads();

    bool colFree = (fc[t >> 5] >> (t & 31)) & 1u;
    int cachedR = sCC[t];
    bool colDirty = colFree &&
        (cachedR < 0 || !((fr[cachedR >> 5] >> (cachedR & 31)) & 1u));
    if (colDirty) {
        float best = -1.f; int bestr = 0x7FFFFFFF;
        int nf2 = nFree;
        int i = 0;
        for (; i + 4 <= nf2; i += 4) {
            int r0 = freeList[i], r1 = freeList[i + 1];
            int r2 = freeList[i + 2], r3 = freeList[i + 3];
            float v0 = Pb[((size_t)r0 << 9) + t];
            float v1 = Pb[((size_t)r1 << 9) + t];
            float v2 = Pb[((size_t)r2 << 9) + t];
            float v3 = Pb[((size_t)r3 << 9) + t];
            if (v0 > best) { best = v0; bestr = r0; }
            if (v1 > best) { best = v1; bestr = r1; }
            if (v2 > best) { best = v2; bestr = r2; }
            if (v3 > best) { best = v3; bestr = r3; }
        }
        for (; i < nf2; ++i) {
            int ri = freeList[i];
            float vv2 = Pb[((size_t)ri << 9) + t];
            if (vv2 > best) { best = vv2; bestr = ri; }
        }
        sCC[t] = bestr;
        rbCc[(b << 9) + t] = bestr;
    }
    __syncthreads();

    if (colFree) {
        int r = sCC[t];
        if (r >= 0 && r < NG && sRC[r] == t) {
            permInt[(b << 9) + r] = t;
            atomicAnd(&fr[r >> 5], ~(1u << (r & 31)));
            atomicAnd(&fc[t >> 5], ~(1u << (t & 31)));
            atomicAdd(&takeCnt, 1);
        }
    }
    __syncthreads();
    if (t < 8) {
        freeRow[b * 8 + t] =
            ((unsigned long long)fr[2 * t + 1] << 32) | fr[2 * t];
    } else if (t < 16) {
        int i = t - 8;
        freeCol[b * 8 + i] =
            ((unsigned long long)fc[2 * i + 1] << 32) | fc[2 * i];
    }
    if (t == 0) remaining[b] = remaining[b] - takeCnt;
}

// ---------------- Exact sequential cleanup (rarely does work).
__global__ __launch_bounds__(64) void greedy_cleanup(
    const float* __restrict__ P,
    const unsigned long long* __restrict__ freeRow,
    const unsigned long long* __restrict__ freeCol,
    const int* __restrict__ remaining, int* __restrict__ permInt)
{
    int b = blockIdx.x;
    if (remaining[b] == 0) return;
    int l = threadIdx.x;
    const float* Pb = P + (size_t)b * NG * NG;

    unsigned long long wR = freeRow[b * 8 + (l >> 3)];
    unsigned int myRows = (unsigned int)((wR >> ((l & 7) * 8)) & 0xFF);
    unsigned long long wC = freeCol[b * 8 + (l >> 3)];
    unsigned int free8 = (unsigned int)((wC >> ((l & 7) * 8)) & 0xFF);

    float rv[8]; int rf[8];
#pragma unroll
    for (int k = 0; k < 8; k++) { rv[k] = -1.f; rf[k] = 0x7FFFFFFF; }

    int dmk = (int)myRows;
    unsigned long long act = __ballot(dmk != 0);
    while (act) {
        int src = __ffsll(act) - 1;
        int kk = __ffs(__builtin_amdgcn_readlane(dmk, src)) - 1;
        if (l == src) dmk &= ~(1 << kk);
        int rr = (src << 3) + kk;
        float nv; int nf;
        masked_row_argmax(Pb + ((size_t)rr << 9), l, free8, rr, nv, nf);
        bool upd = (l == src);
        rv[0] = (upd && kk == 0) ? nv : rv[0]; rf[0] = (upd && kk == 0) ? nf : rf[0];
        rv[1] = (upd && kk == 1) ? nv : rv[1]; rf[1] = (upd && kk == 1) ? nf : rf[1];
        rv[2] = (upd && kk == 2) ? nv : rv[2]; rf[2] = (upd && kk == 2) ? nf : rf[2];
        rv[3] = (upd && kk == 3) ? nv : rv[3]; rf[3] = (upd && kk == 3) ? nf : rf[3];
        rv[4] = (upd && kk == 4) ? nv : rv[4]; rf[4] = (upd && kk == 4) ? nf : rf[4];
        rv[5] = (upd && kk == 5) ? nv : rv[5]; rf[5] = (upd && kk == 5) ? nf : rf[5];
        rv[6] = (upd && kk == 6) ? nv : rv[6]; rf[6] = (upd && kk == 6) ? nf : rf[6];
        rv[7] = (upd && kk == 7) ? nv : rv[7]; rf[7] = (upd && kk == 7) ? nf : rf[7];
        act = __ballot(dmk != 0);
    }

    for (int step = 0; step < NG; ++step) {
        float mv = fmaxf(fmaxf(fmaxf(rv[0], rv[1]), fmaxf(rv[2], rv[3])),
                         fmaxf(fmaxf(rv[4], rv[5]), fmaxf(rv[6], rv[7])));
        int f = 0x7FFFFFFF;
        f = (rv[7] == mv) ? rf[7] : f;
        f = (rv[6] == mv) ? rf[6] : f;
        f = (rv[5] == mv) ? rf[5] : f;
        f = (rv[4] == mv) ? rf[4] : f;
        f = (rv[3] == mv) ? rf[3] : f;
        f = (rv[2] == mv) ? rf[2] : f;
        f = (rv[1] == mv) ? rf[1] : f;
        f = (rv[0] == mv) ? rf[0] : f;
        float g = mv;
        DPP6_MAXF(g)
        int gi = __builtin_amdgcn_readlane(__float_as_int(g), 63);
        float gm = __int_as_float(gi);
        if (gm < 0.f) break;
        unsigned long long tb = __ballot(mv == gm);
        int tl = __ffsll(tb) - 1;
        int bestf = __builtin_amdgcn_readlane(f, tl);
        int r = bestf >> 9, c = bestf & 511;
        if (l == 0) permInt[(b << 9) + r] = c;
        if (l == (c >> 3)) free8 &= ~(1u << (c & 7));
        int rl = r - (l << 3);
        int dm2 = 0;
#pragma unroll
        for (int k = 0; k < 8; k++) {
            bool alive = rv[k] >= 0.f;
            bool cm = ((rf[k] ^ c) & 511) == 0;
            bool taken = (rl == k);
            if (taken) rv[k] = -1.f;
            dm2 |= (alive && cm && !taken) ? (1 << k) : 0;
        }
        unsigned long long act2 = __ballot(dm2 != 0);
        while (act2) {
            int src = __ffsll(act2) - 1;
            int kk = __ffs(__builtin_amdgcn_readlane(dm2, src)) - 1;
            if (l == src) dm2 &= ~(1 << kk);
            int rr = (src << 3) + kk;
            float nv; int nf;
            masked_row_argmax(Pb + ((size_t)rr << 9), l, free8, rr, nv, nf);
            bool upd = (l == src);
            rv[0] = (upd && kk == 0) ? nv : rv[0]; rf[0] = (upd && kk == 0) ? nf : rf[0];
            rv[1] = (upd && kk == 1) ? nv : rv[1]; rf[1] = (upd && kk == 1) ? nf : rf[1];
            rv[2] = (upd && kk == 2) ? nv : rv[2]; rf[2] = (upd && kk == 2) ? nf : rf[2];
            rv[3] = (upd && kk == 3) ? nv : rv[3]; rf[3] = (upd && kk == 3) ? nf : rf[3];
            rv[4] = (upd && kk == 4) ? nv : rv[4]; rf[4] = (upd && kk == 4) ? nf : rf[4];
            rv[5] = (upd && kk == 5) ? nv : rv[5]; rf[5] = (upd && kk == 5) ? nf : rf[5];
            rv[6] = (upd && kk == 6) ? nv : rv[6]; rf[6] = (upd && kk == 6) ? nf : rf[6];
            rv[7] = (upd && kk == 7) ? nv : rv[7]; rf[7] = (upd && kk == 7) ? nf : rf[7];
            act2 = __ballot(dm2 != 0);
        }
    }
}

// ---------------- apply permutation (coords + feats + perm float, fused)
__global__ void scatter_all(const float* __restrict__ coords,
    const float* __restrict__ feats, const int* __restrict__ perm,
    float* __restrict__ dstCoords, float* __restrict__ dstFeats,
    float* __restrict__ permF)
{
    int tid = blockIdx.x * 256 + threadIdx.x;   // NB*NG*96 float4s
    int rc = tid / 96;
    int q = tid - rc * 96;
    int b = rc >> 9;
    int p = perm[rc];
    const float4* s4 = (const float4*)(feats + (size_t)rc * NC);
    float4* d4 = (float4*)(dstFeats + ((size_t)(b << 9) + p) * NC);
    d4[q] = s4[q];
    if (q == 0) {
        permF[rc] = (float)p;
        size_t so = (size_t)rc * 3;
        size_t dd = ((size_t)(b << 9) + p) * 3;
        dstCoords[dd] = coords[so];
        dstCoords[dd + 1] = coords[so + 1];
        dstCoords[dd + 2] = coords[so + 2];
    }
}

extern "C" void kernel_launch(void* const* d_in, const int* in_sizes, int n_in,
                              void* d_out, int out_size, void* d_ws, size_t ws_size,
                              hipStream_t stream)
{
    const float* coords = (const float*)d_in[0];
    const float* feats  = (const float*)d_in[1];
    const float* W1 = (const float*)d_in[2];
    const float* b1 = (const float*)d_in[3];
    const float* W2 = (const float*)d_in[4];
    const float* b2 = (const float*)d_in[5];

    float* out = (float*)d_out;
    float* outCoords = out;
    float* outFeats  = out + (size_t)NB * NG * 3;
    float* outPerm   = out + (size_t)NB * NG * 3 + (size_t)NB * NG * NC;

    float* ws = (float*)d_ws;
    float* h   = ws;                                  // 16384*768 (reused as P)
    float* A0  = h + (size_t)NB * NG * NH;            // 16384*512
    float* u   = A0 + (size_t)NB * NG * NG;           // 16384
    float* v   = u + NB * NG;                         // 16384
    float* pm  = v + NB * NG;                         // 32*8*512 (unused)
    float* ps  = pm + NB * 8 * NG;                    // 32*8*512
    int* rbCr  = (int*)(ps + NB * 8 * NG);            // 16384
    int* rbCc  = rbCr + NB * NG;                      // 16384
    unsigned long long* freeRow = (unsigned long long*)(rbCc + NB * NG); // 256
    unsigned long long* freeCol = freeRow + NB * 8;   // 256
    int* remaining = (int*)(freeCol + NB * 8);        // 32
    int* permInt   = remaining + 32;                  // 16384

    const int M = NB * NG;  // 16384

    // h = relu(feats @ W1 + b1)
    gemm_bias_128<<<dim3((M / 128) * (NH / 128)), 256, 0, stream>>>(
        feats, W1, b1, h, M, NH, NC, 0);
    // A0 = (h @ W2 + b2) / TAU
    gemm_bias_128<<<dim3((M / 128) * (NG / 128)), 256, 0, stream>>>(
        h, W2, b2, A0, M, NG, NH, 1);

    hipMemsetAsync(v, 0, (size_t)NB * NG * sizeof(float), stream);

    for (int it = 0; it < 10; ++it) {
        sinkhorn_iter<<<dim3(NB * 8), 256, 0, stream>>>(A0, u, v, ps);
        col_combine_lin<<<dim3(M / 256), 256, 0, stream>>>(ps, v);
    }

    float* P = h;
    p_rowmax<<<dim3(M / 4), 256, 0, stream>>>(A0, u, v, P, rbCr, rbCc,
                                              freeRow, freeCol, remaining);

    for (int r = 0; r < 10; ++r)
        mutual_round<<<dim3(NB), 512, 0, stream>>>(P, rbCr, rbCc, freeRow,
                                                   freeCol, remaining, permInt);

    greedy_cleanup<<<dim3(NB), 64, 0, stream>>>(P, freeRow, freeCol,
                                                remaining, permInt);

    scatter_all<<<dim3((NB * NG * 96) / 256), 256, 0, stream>>>(
        coords, feats, permInt, outCoords, outFeats, outPerm);
}

// Round 11
// 546.089 us; speedup vs baseline: 2.4430x; 1.0134x over previous
//
#include <hip/hip_runtime.h>
#include <math.h>

#define NB 32
#define NG 512
#define NC 384
#define NH 768

typedef float __attribute__((ext_vector_type(2))) f32x2;

// ---------------- GEMM: C = op(A @ Bw + bias). 128x128 tile, 256 threads,
// 8x8 per thread via f32x2 packed FMA. LDS rows padded to 132.
// __launch_bounds__(256,4): 4 blocks/CU so staging/barrier phases of one
// block overlap FMA phases of another (round-9 theory: barrier-stall bound).
// K order: k0 += 16, kk ascending -> bit-identical outputs vs rounds 6-9.
// mode 0: relu, mode 1: /0.1 (scores/TAU)
__global__ __launch_bounds__(256, 4) void gemm_bias_128(
    const float* __restrict__ A, const float* __restrict__ Bw,
    const float* __restrict__ bias, float* __restrict__ Co,
    int M, int N, int K, int mode)
{
    __shared__ float sA[16][132];
    __shared__ float sB[16][132];
    int ntiles = N >> 7;
    int bm = (blockIdx.x / ntiles) << 7;
    int bn = (blockIdx.x % ntiles) << 7;
    int t = threadIdx.x;
    int tx = t & 15, ty = t >> 4;
    int tr = t >> 2, tc = t & 3;
    const float* Aptr0 = A + (size_t)(bm + tr) * K + 4 * tc;
    const float* Aptr1 = A + (size_t)(bm + 64 + tr) * K + 4 * tc;
    int kb = t >> 4, nc = t & 15;
    const float* BptrL = Bw + (size_t)kb * N + bn + 4 * nc;
    const float* BptrH = Bw + (size_t)kb * N + bn + 64 + 4 * nc;

    f32x2 acc2[8][4];
#pragma unroll
    for (int i = 0; i < 8; i++)
#pragma unroll
        for (int j = 0; j < 4; j++) acc2[i][j] = (f32x2)(0.f);

    for (int k0 = 0; k0 < K; k0 += 16) {
        float4 a0 = *(const float4*)(Aptr0 + k0);
        float4 a1 = *(const float4*)(Aptr1 + k0);
        float4 b0 = *(const float4*)(BptrL + (size_t)k0 * N);
        float4 b1 = *(const float4*)(BptrH + (size_t)k0 * N);
        __syncthreads();
        sA[4 * tc + 0][tr] = a0.x;
        sA[4 * tc + 1][tr] = a0.y;
        sA[4 * tc + 2][tr] = a0.z;
        sA[4 * tc + 3][tr] = a0.w;
        sA[4 * tc + 0][64 + tr] = a1.x;
        sA[4 * tc + 1][64 + tr] = a1.y;
        sA[4 * tc + 2][64 + tr] = a1.z;
        sA[4 * tc + 3][64 + tr] = a1.w;
        *(float4*)&sB[kb][4 * nc] = b0;
        *(float4*)&sB[kb][64 + 4 * nc] = b1;
        __syncthreads();
#pragma unroll
        for (int kk = 0; kk < 16; kk++) {
            float4 aL = *(const float4*)&sA[kk][4 * ty];
            float4 aH = *(const float4*)&sA[kk][64 + 4 * ty];
            float4 bL = *(const float4*)&sB[kk][4 * tx];
            float4 bH = *(const float4*)&sB[kk][64 + 4 * tx];
            float av[8] = { aL.x, aL.y, aL.z, aL.w, aH.x, aH.y, aH.z, aH.w };
            f32x2 bb[4];
            bb[0].x = bL.x; bb[0].y = bL.y;
            bb[1].x = bL.z; bb[1].y = bL.w;
            bb[2].x = bH.x; bb[2].y = bH.y;
            bb[3].x = bH.z; bb[3].y = bH.w;
#pragma unroll
            for (int i = 0; i < 8; i++) {
                f32x2 aa; aa.x = av[i]; aa.y = av[i];
#pragma unroll
                for (int j = 0; j < 4; j++)
                    acc2[i][j] = __builtin_elementwise_fma(aa, bb[j], acc2[i][j]);
            }
        }
    }

    float4 blo = *(const float4*)(bias + bn + 4 * tx);
    float4 bhi = *(const float4*)(bias + bn + 64 + 4 * tx);
    float bb8[8] = { blo.x, blo.y, blo.z, blo.w, bhi.x, bhi.y, bhi.z, bhi.w };
#pragma unroll
    for (int i = 0; i < 8; i++) {
        int row = bm + ((i < 4) ? (4 * ty + i) : (64 + 4 * ty + i - 4));
        float vals[8];
        vals[0] = acc2[i][0].x + bb8[0];
        vals[1] = acc2[i][0].y + bb8[1];
        vals[2] = acc2[i][1].x + bb8[2];
        vals[3] = acc2[i][1].y + bb8[3];
        vals[4] = acc2[i][2].x + bb8[4];
        vals[5] = acc2[i][2].y + bb8[5];
        vals[6] = acc2[i][3].x + bb8[6];
        vals[7] = acc2[i][3].y + bb8[7];
#pragma unroll
        for (int j = 0; j < 8; j++)
            vals[j] = (mode == 0) ? fmaxf(vals[j], 0.f) : vals[j] / 0.1f;
        float4 oL; oL.x = vals[0]; oL.y = vals[1]; oL.z = vals[2]; oL.w = vals[3];
        float4 oH; oH.x = vals[4]; oH.y = vals[5]; oH.z = vals[6]; oH.w = vals[7];
        *(float4*)(Co + (size_t)row * N + bn + 4 * tx) = oL;
        *(float4*)(Co + (size_t)row * N + bn + 64 + 4 * tx) = oH;
    }
}

// ======== DPP reduce networks to lane 63 (pure VALU) ========
#define DPP6_MAXF(x)                                                              \
    { int _t;                                                                     \
      _t = __builtin_amdgcn_update_dpp(__float_as_int(x), __float_as_int(x),      \
               0x111, 0xf, 0xf, false); x = fmaxf(x, __int_as_float(_t));         \
      _t = __builtin_amdgcn_update_dpp(__float_as_int(x), __float_as_int(x),      \
               0x112, 0xf, 0xf, false); x = fmaxf(x, __int_as_float(_t));         \
      _t = __builtin_amdgcn_update_dpp(__float_as_int(x), __float_as_int(x),      \
               0x114, 0xf, 0xf, false); x = fmaxf(x, __int_as_float(_t));         \
      _t = __builtin_amdgcn_update_dpp(__float_as_int(x), __float_as_int(x),      \
               0x118, 0xf, 0xf, false); x = fmaxf(x, __int_as_float(_t));         \
      _t = __builtin_amdgcn_update_dpp(__float_as_int(x), __float_as_int(x),      \
               0x142, 0xa, 0xf, false); x = fmaxf(x, __int_as_float(_t));         \
      _t = __builtin_amdgcn_update_dpp(__float_as_int(x), __float_as_int(x),      \
               0x143, 0xc, 0xf, false); x = fmaxf(x, __int_as_float(_t)); }

#define DPP6_ADDF(x)                                                              \
    { int _t;                                                                     \
      _t = __builtin_amdgcn_update_dpp(__float_as_int(x), __float_as_int(x),      \
               0x111, 0xf, 0xf, false); x = x + __int_as_float(_t);               \
      _t = __builtin_amdgcn_update_dpp(__float_as_int(x), __float_as_int(x),      \
               0x112, 0xf, 0xf, false); x = x + __int_as_float(_t);               \
      _t = __builtin_amdgcn_update_dpp(__float_as_int(x), __float_as_int(x),      \
               0x114, 0xf, 0xf, false); x = x + __int_as_float(_t);               \
      _t = __builtin_amdgcn_update_dpp(__float_as_int(x), __float_as_int(x),      \
               0x118, 0xf, 0xf, false); x = x + __int_as_float(_t);               \
      _t = __builtin_amdgcn_update_dpp(__float_as_int(x), __float_as_int(x),      \
               0x142, 0xa, 0xf, false); x = x + __int_as_float(_t);               \
      _t = __builtin_amdgcn_update_dpp(__float_as_int(x), __float_as_int(x),      \
               0x143, 0xc, 0xf, false); x = x + __int_as_float(_t); }

// ---------------- Fused Sinkhorn half-iterations (see round-9 notes).
__global__ __launch_bounds__(256) void sinkhorn_iter(
    const float* __restrict__ A0, float* __restrict__ uu,
    const float* __restrict__ vv, float* __restrict__ ps)
{
    int blk = blockIdx.x;          // NB*8
    int b = blk >> 3, rc = blk & 7;
    int t = threadIdx.x;
    int l = t & 63, w = t >> 6;
    const float* vb = vv + (b << 9);
    float4 v0 = *(const float4*)(vb + 4 * l);
    float4 v1 = *(const float4*)(vb + 256 + 4 * l);
    int row0 = (rc << 6) + (w << 4);
    const float* base = A0 + ((size_t)((b << 9) + row0) << 9);

    float cs0 = 0.f, cs1 = 0.f, cs2 = 0.f, cs3 = 0.f;
    float cs4 = 0.f, cs5 = 0.f, cs6 = 0.f, cs7 = 0.f;

    for (int rr = 0; rr < 16; ++rr) {
        const float* rowp = base + ((size_t)rr << 9);
        float4 a0 = *(const float4*)(rowp + 4 * l);
        float4 a1 = *(const float4*)(rowp + 256 + 4 * l);
        float x0 = a0.x + v0.x, x1 = a0.y + v0.y;
        float x2 = a0.z + v0.z, x3 = a0.w + v0.w;
        float x4 = a1.x + v1.x, x5 = a1.y + v1.y;
        float x6 = a1.z + v1.z, x7 = a1.w + v1.w;
        float m = fmaxf(fmaxf(fmaxf(x0, x1), fmaxf(x2, x3)),
                        fmaxf(fmaxf(x4, x5), fmaxf(x6, x7)));
        DPP6_MAXF(m)
        int mi = __builtin_amdgcn_readlane(__float_as_int(m), 63);
        m = __int_as_float(mi);
        float e0 = __expf(x0 - m), e1 = __expf(x1 - m);
        float e2 = __expf(x2 - m), e3 = __expf(x3 - m);
        float e4 = __expf(x4 - m), e5 = __expf(x5 - m);
        float e6 = __expf(x6 - m), e7 = __expf(x7 - m);
        float s = ((e0 + e1) + (e2 + e3)) + ((e4 + e5) + (e6 + e7));
        DPP6_ADDF(s)
        int si = __builtin_amdgcn_readlane(__float_as_int(s), 63);
        s = __int_as_float(si);
        float inv = 1.0f / s;
        cs0 += e0 * inv; cs1 += e1 * inv; cs2 += e2 * inv; cs3 += e3 * inv;
        cs4 += e4 * inv; cs5 += e5 * inv; cs6 += e6 * inv; cs7 += e7 * inv;
        if (l == 63) uu[(b << 9) + row0 + rr] = -(m + __logf(s));
    }

    __shared__ float sacc[4][512];
    float4 w0; w0.x = cs0; w0.y = cs1; w0.z = cs2; w0.w = cs3;
    float4 w1; w1.x = cs4; w1.y = cs5; w1.z = cs6; w1.w = cs7;
    *(float4*)&sacc[w][4 * l] = w0;
    *(float4*)&sacc[w][256 + 4 * l] = w1;
    __syncthreads();
    float pA = sacc[0][t] + sacc[1][t] + sacc[2][t] + sacc[3][t];
    float pB = sacc[0][256 + t] + sacc[1][256 + t] + sacc[2][256 + t] + sacc[3][256 + t];
    int o = ((b << 3) + rc) * NG;
    ps[o + t] = pA;
    ps[o + 256 + t] = pB;
}

// ---------------- combine 8 linear partials -> v' = v - log(colsum)
__global__ __launch_bounds__(256) void col_combine_lin(
    const float* __restrict__ ps, float* __restrict__ vv)
{
    int tid = blockIdx.x * 256 + threadIdx.x;  // NB*NG
    int b = tid >> 9, j = tid & 511;
    float S = 0.f;
#pragma unroll
    for (int rc = 0; rc < 8; rc++) S += ps[((b << 3) + rc) * NG + j];
    vv[tid] = vv[tid] - __logf(S);
}

// wave-cooperative masked row argmax over cols 8l..8l+7 per lane.
__device__ __forceinline__ void masked_row_argmax(
    const float* __restrict__ rowp, int l, unsigned int free8, int rr,
    float& outV, int& outF)
{
    float4 x0 = *(const float4*)(rowp + 8 * l);
    float4 x1 = *(const float4*)(rowp + 8 * l + 4);
    float q0 = (free8 & 1u)   ? x0.x : -1.0f;
    float q1 = (free8 & 2u)   ? x0.y : -1.0f;
    float q2 = (free8 & 4u)   ? x0.z : -1.0f;
    float q3 = (free8 & 8u)   ? x0.w : -1.0f;
    float q4 = (free8 & 16u)  ? x1.x : -1.0f;
    float q5 = (free8 & 32u)  ? x1.y : -1.0f;
    float q6 = (free8 & 64u)  ? x1.z : -1.0f;
    float q7 = (free8 & 128u) ? x1.w : -1.0f;
    float lm = fmaxf(fmaxf(fmaxf(q0, q1), fmaxf(q2, q3)),
                     fmaxf(fmaxf(q4, q5), fmaxf(q6, q7)));
    int sb = (rr << 9) + 8 * l;
    int lf = 0x7FFFFFFF;
    lf = (q7 == lm) ? sb + 7 : lf;
    lf = (q6 == lm) ? sb + 6 : lf;
    lf = (q5 == lm) ? sb + 5 : lf;
    lf = (q4 == lm) ? sb + 4 : lf;
    lf = (q3 == lm) ? sb + 3 : lf;
    lf = (q2 == lm) ? sb + 2 : lf;
    lf = (q1 == lm) ? sb + 1 : lf;
    lf = (q0 == lm) ? sb + 0 : lf;
    float gg = lm;
    DPP6_MAXF(gg)
    int ggi = __builtin_amdgcn_readlane(__float_as_int(gg), 63);
    float g1 = __int_as_float(ggi);
    unsigned long long tb = __ballot(lm == g1);
    int tl = __ffsll(tb) - 1;
    outV = g1;
    outF = __builtin_amdgcn_readlane(lf, tl);
}

// ---------------- P = exp((A0+u)+v) (libm expf) + per-row argmax + state init.
__global__ __launch_bounds__(256) void p_rowmax(
    const float* __restrict__ A0, const float* __restrict__ uu,
    const float* __restrict__ vv, float* __restrict__ P,
    int* __restrict__ rbCr, int* __restrict__ rbCc,
    unsigned long long* __restrict__ freeRow,
    unsigned long long* __restrict__ freeCol,
    int* __restrict__ remaining)
{
    if (blockIdx.x == 0) {
        int t = threadIdx.x;
        freeRow[t] = ~0ULL;
        freeCol[t] = ~0ULL;
        if (t < NB) remaining[t] = NG;
    }
    int wrow = blockIdx.x * 4 + (threadIdx.x >> 6);
    int l = threadIdx.x & 63;
    int b = wrow >> 9;
    float ur = uu[wrow];
    const float* vb = vv + (b << 9);
    size_t ro = (size_t)wrow << 9;
    float4 a0 = *(const float4*)(A0 + ro + 8 * l);
    float4 a1 = *(const float4*)(A0 + ro + 8 * l + 4);
    float4 v0 = *(const float4*)(vb + 8 * l);
    float4 v1 = *(const float4*)(vb + 8 * l + 4);
    float p0 = expf(a0.x + ur + v0.x);
    float p1 = expf(a0.y + ur + v0.y);
    float p2 = expf(a0.z + ur + v0.z);
    float p3 = expf(a0.w + ur + v0.w);
    float p4 = expf(a1.x + ur + v1.x);
    float p5 = expf(a1.y + ur + v1.y);
    float p6 = expf(a1.z + ur + v1.z);
    float p7 = expf(a1.w + ur + v1.w);
    float4 o0; o0.x = p0; o0.y = p1; o0.z = p2; o0.w = p3;
    float4 o1; o1.x = p4; o1.y = p5; o1.z = p6; o1.w = p7;
    *(float4*)(P + ro + 8 * l) = o0;
    *(float4*)(P + ro + 8 * l + 4) = o1;
    float mv = fmaxf(fmaxf(fmaxf(p0, p1), fmaxf(p2, p3)),
                     fmaxf(fmaxf(p4, p5), fmaxf(p6, p7)));
    int cb = 8 * l;
    int f = 0x7FFFFFFF;
    f = (p7 == mv) ? cb + 7 : f;
    f = (p6 == mv) ? cb + 6 : f;
    f = (p5 == mv) ? cb + 5 : f;
    f = (p4 == mv) ? cb + 4 : f;
    f = (p3 == mv) ? cb + 3 : f;
    f = (p2 == mv) ? cb + 2 : f;
    f = (p1 == mv) ? cb + 1 : f;
    f = (p0 == mv) ? cb + 0 : f;
    float g = mv;
    DPP6_MAXF(g)
    int gi = __builtin_amdgcn_readlane(__float_as_int(g), 63);
    float gm = __int_as_float(gi);
    unsigned long long tb = __ballot(mv == gm);
    int tl = __ffsll(tb) - 1;
    int bestc = __builtin_amdgcn_readlane(f, tl);
    if (l == 0) { rbCr[wrow] = bestc; rbCc[wrow] = -1; }
}

// ---------------- One parallel mutual-max round (exact greedy equivalence).
__global__ __launch_bounds__(512) void mutual_round(
    const float* __restrict__ P, int* __restrict__ rbCr, int* __restrict__ rbCc,
    unsigned long long* __restrict__ freeRow,
    unsigned long long* __restrict__ freeCol,
    int* __restrict__ remaining, int* __restrict__ permInt)
{
    int b = blockIdx.x;
    if (remaining[b] == 0) return;
    int t = threadIdx.x;
    int l = t & 63;
    int w = t >> 6;
    const float* Pb = P + (size_t)b * NG * NG;

    __shared__ unsigned int fr[16], fc[16];
    __shared__ int sRC[NG];
    __shared__ int sCC[NG];
    __shared__ int freeList[NG];
    __shared__ int dirtyRows[NG];
    __shared__ int nFree, nDirtyRow, takeCnt;
    __shared__ int wCnt[8], wOff[8];

    if (t < 8) {
        unsigned long long x = freeRow[b * 8 + t];
        fr[2 * t] = (unsigned)x; fr[2 * t + 1] = (unsigned)(x >> 32);
    } else if (t < 16) {
        int i = t - 8;
        unsigned long long x = freeCol[b * 8 + i];
        fc[2 * i] = (unsigned)x; fc[2 * i + 1] = (unsigned)(x >> 32);
    }
    sRC[t] = rbCr[(b << 9) + t];
    sCC[t] = rbCc[(b << 9) + t];
    if (t == 0) { nDirtyRow = 0; takeCnt = 0; }
    __syncthreads();

    bool isFree = (fr[t >> 5] >> (t & 31)) & 1u;
    unsigned long long bm = __ballot(isFree);
    if (l == 0) wCnt[w] = __popcll(bm);
    if (isFree) {
        int c = sRC[t];
        if (!((fc[c >> 5] >> (c & 31)) & 1u)) {
            int d = atomicAdd(&nDirtyRow, 1);
            dirtyRows[d] = t;
        }
    }
    __syncthreads();
    if (t == 0) {
        int s = 0;
#pragma unroll
        for (int i = 0; i < 8; i++) { wOff[i] = s; s += wCnt[i]; }
        nFree = s;
    }
    __syncthreads();
    if (isFree) {
        int rank = __popcll(bm & ((1ULL << l) - 1ULL));
        freeList[wOff[w] + rank] = t;
    }
    __syncthreads();

    int nd = nDirtyRow;
    for (int d = w; d < nd; d += 8) {
        int r = dirtyRows[d];
        unsigned int free8 = (fc[l >> 2] >> ((l & 3) * 8)) & 0xFFu;
        float nv; int nf;
        masked_row_argmax(Pb + ((size_t)r << 9), l, free8, r, nv, nf);
        if (l == 0) {
            int c = nf & 511;
            sRC[r] = c;
            rbCr[(b << 9) + r] = c;
        }
    }
    __syncthreads();

    bool colFree = (fc[t >> 5] >> (t & 31)) & 1u;
    int cachedR = sCC[t];
    bool colDirty = colFree &&
        (cachedR < 0 || !((fr[cachedR >> 5] >> (cachedR & 31)) & 1u));
    if (colDirty) {
        float best = -1.f; int bestr = 0x7FFFFFFF;
        int nf2 = nFree;
        int i = 0;
        for (; i + 4 <= nf2; i += 4) {
            int r0 = freeList[i], r1 = freeList[i + 1];
            int r2 = freeList[i + 2], r3 = freeList[i + 3];
            float v0 = Pb[((size_t)r0 << 9) + t];
            float v1 = Pb[((size_t)r1 << 9) + t];
            float v2 = Pb[((size_t)r2 << 9) + t];
            float v3 = Pb[((size_t)r3 << 9) + t];
            if (v0 > best) { best = v0; bestr = r0; }
            if (v1 > best) { best = v1; bestr = r1; }
            if (v2 > best) { best = v2; bestr = r2; }
            if (v3 > best) { best = v3; bestr = r3; }
        }
        for (; i < nf2; ++i) {
            int ri = freeList[i];
            float vv2 = Pb[((size_t)ri << 9) + t];
            if (vv2 > best) { best = vv2; bestr = ri; }
        }
        sCC[t] = bestr;
        rbCc[(b << 9) + t] = bestr;
    }
    __syncthreads();

    if (colFree) {
        int r = sCC[t];
        if (r >= 0 && r < NG && sRC[r] == t) {
            permInt[(b << 9) + r] = t;
            atomicAnd(&fr[r >> 5], ~(1u << (r & 31)));
            atomicAnd(&fc[t >> 5], ~(1u << (t & 31)));
            atomicAdd(&takeCnt, 1);
        }
    }
    __syncthreads();
    if (t < 8) {
        freeRow[b * 8 + t] =
            ((unsigned long long)fr[2 * t + 1] << 32) | fr[2 * t];
    } else if (t < 16) {
        int i = t - 8;
        freeCol[b * 8 + i] =
            ((unsigned long long)fc[2 * i + 1] << 32) | fc[2 * i];
    }
    if (t == 0) remaining[b] = remaining[b] - takeCnt;
}

// ---------------- Exact sequential cleanup (rarely does work).
__global__ __launch_bounds__(64) void greedy_cleanup(
    const float* __restrict__ P,
    const unsigned long long* __restrict__ freeRow,
    const unsigned long long* __restrict__ freeCol,
    const int* __restrict__ remaining, int* __restrict__ permInt)
{
    int b = blockIdx.x;
    if (remaining[b] == 0) return;
    int l = threadIdx.x;
    const float* Pb = P + (size_t)b * NG * NG;

    unsigned long long wR = freeRow[b * 8 + (l >> 3)];
    unsigned int myRows = (unsigned int)((wR >> ((l & 7) * 8)) & 0xFF);
    unsigned long long wC = freeCol[b * 8 + (l >> 3)];
    unsigned int free8 = (unsigned int)((wC >> ((l & 7) * 8)) & 0xFF);

    float rv[8]; int rf[8];
#pragma unroll
    for (int k = 0; k < 8; k++) { rv[k] = -1.f; rf[k] = 0x7FFFFFFF; }

    int dmk = (int)myRows;
    unsigned long long act = __ballot(dmk != 0);
    while (act) {
        int src = __ffsll(act) - 1;
        int kk = __ffs(__builtin_amdgcn_readlane(dmk, src)) - 1;
        if (l == src) dmk &= ~(1 << kk);
        int rr = (src << 3) + kk;
        float nv; int nf;
        masked_row_argmax(Pb + ((size_t)rr << 9), l, free8, rr, nv, nf);
        bool upd = (l == src);
        rv[0] = (upd && kk == 0) ? nv : rv[0]; rf[0] = (upd && kk == 0) ? nf : rf[0];
        rv[1] = (upd && kk == 1) ? nv : rv[1]; rf[1] = (upd && kk == 1) ? nf : rf[1];
        rv[2] = (upd && kk == 2) ? nv : rv[2]; rf[2] = (upd && kk == 2) ? nf : rf[2];
        rv[3] = (upd && kk == 3) ? nv : rv[3]; rf[3] = (upd && kk == 3) ? nf : rf[3];
        rv[4] = (upd && kk == 4) ? nv : rv[4]; rf[4] = (upd && kk == 4) ? nf : rf[4];
        rv[5] = (upd && kk == 5) ? nv : rv[5]; rf[5] = (upd && kk == 5) ? nf : rf[5];
        rv[6] = (upd && kk == 6) ? nv : rv[6]; rf[6] = (upd && kk == 6) ? nf : rf[6];
        rv[7] = (upd && kk == 7) ? nv : rv[7]; rf[7] = (upd && kk == 7) ? nf : rf[7];
        act = __ballot(dmk != 0);
    }

    for (int step = 0; step < NG; ++step) {
        float mv = fmaxf(fmaxf(fmaxf(rv[0], rv[1]), fmaxf(rv[2], rv[3])),
                         fmaxf(fmaxf(rv[4], rv[5]), fmaxf(rv[6], rv[7])));
        int f = 0x7FFFFFFF;
        f = (rv[7] == mv) ? rf[7] : f;
        f = (rv[6] == mv) ? rf[6] : f;
        f = (rv[5] == mv) ? rf[5] : f;
        f = (rv[4] == mv) ? rf[4] : f;
        f = (rv[3] == mv) ? rf[3] : f;
        f = (rv[2] == mv) ? rf[2] : f;
        f = (rv[1] == mv) ? rf[1] : f;
        f = (rv[0] == mv) ? rf[0] : f;
        float g = mv;
        DPP6_MAXF(g)
        int gi = __builtin_amdgcn_readlane(__float_as_int(g), 63);
        float gm = __int_as_float(gi);
        if (gm < 0.f) break;
        unsigned long long tb = __ballot(mv == gm);
        int tl = __ffsll(tb) - 1;
        int bestf = __builtin_amdgcn_readlane(f, tl);
        int r = bestf >> 9, c = bestf & 511;
        if (l == 0) permInt[(b << 9) + r] = c;
        if (l == (c >> 3)) free8 &= ~(1u << (c & 7));
        int rl = r - (l << 3);
        int dm2 = 0;
#pragma unroll
        for (int k = 0; k < 8; k++) {
            bool alive = rv[k] >= 0.f;
            bool cm = ((rf[k] ^ c) & 511) == 0;
            bool taken = (rl == k);
            if (taken) rv[k] = -1.f;
            dm2 |= (alive && cm && !taken) ? (1 << k) : 0;
        }
        unsigned long long act2 = __ballot(dm2 != 0);
        while (act2) {
            int src = __ffsll(act2) - 1;
            int kk = __ffs(__builtin_amdgcn_readlane(dm2, src)) - 1;
            if (l == src) dm2 &= ~(1 << kk);
            int rr = (src << 3) + kk;
            float nv; int nf;
            masked_row_argmax(Pb + ((size_t)rr << 9), l, free8, rr, nv, nf);
            bool upd = (l == src);
            rv[0] = (upd && kk == 0) ? nv : rv[0]; rf[0] = (upd && kk == 0) ? nf : rf[0];
            rv[1] = (upd && kk == 1) ? nv : rv[1]; rf[1] = (upd && kk == 1) ? nf : rf[1];
            rv[2] = (upd && kk == 2) ? nv : rv[2]; rf[2] = (upd && kk == 2) ? nf : rf[2];
            rv[3] = (upd && kk == 3) ? nv : rv[3]; rf[3] = (upd && kk == 3) ? nf : rf[3];
            rv[4] = (upd && kk == 4) ? nv : rv[4]; rf[4] = (upd && kk == 4) ? nf : rf[4];
            rv[5] = (upd && kk == 5) ? nv : rv[5]; rf[5] = (upd && kk == 5) ? nf : rf[5];
            rv[6] = (upd && kk == 6) ? nv : rv[6]; rf[6] = (upd && kk == 6) ? nf : rf[6];
            rv[7] = (upd && kk == 7) ? nv : rv[7]; rf[7] = (upd && kk == 7) ? nf : rf[7];
            act2 = __ballot(dm2 != 0);
        }
    }
}

// ---------------- apply permutation (coords + feats + perm float, fused)
__global__ void scatter_all(const float* __restrict__ coords,
    const float* __restrict__ feats, const int* __restrict__ perm,
    float* __restrict__ dstCoords, float* __restrict__ dstFeats,
    float* __restrict__ permF)
{
    int tid = blockIdx.x * 256 + threadIdx.x;   // NB*NG*96 float4s
    int rc = tid / 96;
    int q = tid - rc * 96;
    int b = rc >> 9;
    int p = perm[rc];
    const float4* s4 = (const float4*)(feats + (size_t)rc * NC);
    float4* d4 = (float4*)(dstFeats + ((size_t)(b << 9) + p) * NC);
    d4[q] = s4[q];
    if (q == 0) {
        permF[rc] = (float)p;
        size_t so = (size_t)rc * 3;
        size_t dd = ((size_t)(b << 9) + p) * 3;
        dstCoords[dd] = coords[so];
        dstCoords[dd + 1] = coords[so + 1];
        dstCoords[dd + 2] = coords[so + 2];
    }
}

extern "C" void kernel_launch(void* const* d_in, const int* in_sizes, int n_in,
                              void* d_out, int out_size, void* d_ws, size_t ws_size,
                              hipStream_t stream)
{
    const float* coords = (const float*)d_in[0];
    const float* feats  = (const float*)d_in[1];
    const float* W1 = (const float*)d_in[2];
    const float* b1 = (const float*)d_in[3];
    const float* W2 = (const float*)d_in[4];
    const float* b2 = (const float*)d_in[5];

    float* out = (float*)d_out;
    float* outCoords = out;
    float* outFeats  = out + (size_t)NB * NG * 3;
    float* outPerm   = out + (size_t)NB * NG * 3 + (size_t)NB * NG * NC;

    float* ws = (float*)d_ws;
    float* h   = ws;                                  // 16384*768 (reused as P)
    float* A0  = h + (size_t)NB * NG * NH;            // 16384*512
    float* u   = A0 + (size_t)NB * NG * NG;           // 16384
    float* v   = u + NB * NG;                         // 16384
    float* pm  = v + NB * NG;                         // 32*8*512 (unused)
    float* ps  = pm + NB * 8 * NG;                    // 32*8*512
    int* rbCr  = (int*)(ps + NB * 8 * NG);            // 16384
    int* rbCc  = rbCr + NB * NG;                      // 16384
    unsigned long long* freeRow = (unsigned long long*)(rbCc + NB * NG); // 256
    unsigned long long* freeCol = freeRow + NB * 8;   // 256
    int* remaining = (int*)(freeCol + NB * 8);        // 32
    int* permInt   = remaining + 32;                  // 16384

    const int M = NB * NG;  // 16384

    // h = relu(feats @ W1 + b1)
    gemm_bias_128<<<dim3((M / 128) * (NH / 128)), 256, 0, stream>>>(
        feats, W1, b1, h, M, NH, NC, 0);
    // A0 = (h @ W2 + b2) / TAU
    gemm_bias_128<<<dim3((M / 128) * (NG / 128)), 256, 0, stream>>>(
        h, W2, b2, A0, M, NG, NH, 1);

    hipMemsetAsync(v, 0, (size_t)NB * NG * sizeof(float), stream);

    for (int it = 0; it < 10; ++it) {
        sinkhorn_iter<<<dim3(NB * 8), 256, 0, stream>>>(A0, u, v, ps);
        col_combine_lin<<<dim3(M / 256), 256, 0, stream>>>(ps, v);
    }

    float* P = h;
    p_rowmax<<<dim3(M / 4), 256, 0, stream>>>(A0, u, v, P, rbCr, rbCc,
                                              freeRow, freeCol, remaining);

    for (int r = 0; r < 6; ++r)
        mutual_round<<<dim3(NB), 512, 0, stream>>>(P, rbCr, rbCc, freeRow,
                                                   freeCol, remaining, permInt);

    greedy_cleanup<<<dim3(NB), 64, 0, stream>>>(P, freeRow, freeCol,
                                                remaining, permInt);

    scatter_all<<<dim3((NB * NG * 96) / 256), 256, 0, stream>>>(
        coords, feats, permInt, outCoords, outFeats, outPerm);
}